// Round 1
// baseline (3130.036 us; speedup 1.0000x reference)
//
#include <hip/hip_runtime.h>
#include <hip/hip_bf16.h>

#define NHEADS 4
#define DIM 128
#define NEG_SLOPE 0.2f

__device__ __forceinline__ unsigned encF(float f) {
    unsigned u = __float_as_uint(f);
    return (u & 0x80000000u) ? ~u : (u | 0x80000000u);
}
__device__ __forceinline__ float decF(unsigned u) {
    return __uint_as_float((u & 0x80000000u) ? (u & 0x7fffffffu) : ~u);
}
__device__ __forceinline__ float lrelu(float x) { return x > 0.f ? x : NEG_SLOPE * x; }

// ---------------- GEMM: out[n][j] = sum_k relu?(in[n][k]) * W[j][k] + b[j] -------------
// 64-row x 128-col tile per block, 256 threads, BK=32, LDS-staged, fp32 FMA.
template<bool RELU_IN>
__global__ __launch_bounds__(256) void gemm_nodes(
    const float* __restrict__ in, const float* __restrict__ W,
    const float* __restrict__ bias, float* __restrict__ out, int n)
{
    __shared__ float As[32][68];    // [k][m], padded
    __shared__ float Bs[32][132];   // [k][j], padded
    const int tid = threadIdx.x;
    const int ty = tid >> 4, tx = tid & 15;
    const int n0 = blockIdx.x * 64;

    float acc[4][8];
#pragma unroll
    for (int i = 0; i < 4; ++i)
#pragma unroll
        for (int j = 0; j < 8; ++j) acc[i][j] = 0.f;

    const int arow = tid >> 2, ak0 = (tid & 3) * 8;   // A: 8 floats each
    const int bj = tid >> 1, bk0 = (tid & 1) * 16;    // B: 16 floats each

    for (int k0 = 0; k0 < DIM; k0 += 32) {
        float v[8];
        if (n0 + arow < n) {
            const float* p = in + (size_t)(n0 + arow) * DIM + k0 + ak0;
            float4 x0 = *(const float4*)p;
            float4 x1 = *(const float4*)(p + 4);
            v[0]=x0.x; v[1]=x0.y; v[2]=x0.z; v[3]=x0.w;
            v[4]=x1.x; v[5]=x1.y; v[6]=x1.z; v[7]=x1.w;
            if (RELU_IN) {
#pragma unroll
                for (int i = 0; i < 8; ++i) v[i] = fmaxf(v[i], 0.f);
            }
        } else {
#pragma unroll
            for (int i = 0; i < 8; ++i) v[i] = 0.f;
        }
#pragma unroll
        for (int i = 0; i < 8; ++i) As[ak0 + i][arow] = v[i];

        {
            const float* p = W + (size_t)bj * DIM + k0 + bk0;
#pragma unroll
            for (int q = 0; q < 4; ++q) {
                float4 x = *(const float4*)(p + q * 4);
                Bs[bk0 + q*4 + 0][bj] = x.x; Bs[bk0 + q*4 + 1][bj] = x.y;
                Bs[bk0 + q*4 + 2][bj] = x.z; Bs[bk0 + q*4 + 3][bj] = x.w;
            }
        }
        __syncthreads();
#pragma unroll
        for (int kk = 0; kk < 32; ++kk) {
            float4 a  = *(const float4*)&As[kk][ty * 4];
            float4 b0 = *(const float4*)&Bs[kk][tx * 4];
            float4 b1 = *(const float4*)&Bs[kk][64 + tx * 4];
            float av[4] = {a.x, a.y, a.z, a.w};
            float bv[8] = {b0.x, b0.y, b0.z, b0.w, b1.x, b1.y, b1.z, b1.w};
#pragma unroll
            for (int i = 0; i < 4; ++i)
#pragma unroll
                for (int j = 0; j < 8; ++j)
                    acc[i][j] = fmaf(av[i], bv[j], acc[i][j]);
        }
        __syncthreads();
    }
#pragma unroll
    for (int i = 0; i < 4; ++i) {
        int row = n0 + ty * 4 + i;
        if (row < n) {
            float* po = out + (size_t)row * DIM;
#pragma unroll
            for (int j = 0; j < 4; ++j) {
                po[tx*4 + j]      = acc[i][j]     + bias[tx*4 + j];
                po[64 + tx*4 + j] = acc[i][j + 4] + bias[64 + tx*4 + j];
            }
        }
    }
}

// ---------------- per-node attention coefficients ----------------
// one wave per node; att arrays are flat [H*C]=[128] indexable by channel.
__global__ __launch_bounds__(256) void alpha_nodes(
    const float* __restrict__ xl, const float* __restrict__ attl,
    const float* __restrict__ attr, float* __restrict__ al,
    float* __restrict__ ar, int n)
{
    int node = blockIdx.x * 4 + (threadIdx.x >> 6);
    if (node >= n) return;
    int lane = threadIdx.x & 63;
    float v0 = xl[(size_t)node * DIM + lane];
    float v1 = xl[(size_t)node * DIM + 64 + lane];
    float l0 = v0 * attl[lane],      r0 = v0 * attr[lane];
    float l1 = v1 * attl[64 + lane], r1 = v1 * attr[64 + lane];
#pragma unroll
    for (int off = 16; off >= 1; off >>= 1) {
        l0 += __shfl_xor(l0, off); r0 += __shfl_xor(r0, off);
        l1 += __shfl_xor(l1, off); r1 += __shfl_xor(r1, off);
    }
    if ((lane & 31) == 0) {
        int h = lane >> 5;  // 0 or 1
        al[node*4 + h]     = l0; ar[node*4 + h]     = r0;
        al[node*4 + 2 + h] = l1; ar[node*4 + 2 + h] = r1;
    }
}

// ---------------- edge pass 1: segment max (encoded-uint atomicMax) -------------
__global__ __launch_bounds__(256) void edge_max(
    const int* __restrict__ src, const int* __restrict__ dst,
    const float* __restrict__ al, const float* __restrict__ ar,
    unsigned* __restrict__ menc, int E)
{
    int e = blockIdx.x * blockDim.x + threadIdx.x;
    if (e >= E) return;
    int s = src[e], d = dst[e];
    const float4 a_l = *(const float4*)(al + (size_t)s * 4);
    const float4 a_r = *(const float4*)(ar + (size_t)d * 4);
    float ev[4] = {a_r.x + a_l.x, a_r.y + a_l.y, a_r.z + a_l.z, a_r.w + a_l.w};
#pragma unroll
    for (int h = 0; h < 4; ++h) atomicMax(&menc[d*4 + h], encF(lrelu(ev[h])));
}

// ---------------- edge pass 2: segment sum of exp ----------------
__global__ __launch_bounds__(256) void edge_sum(
    const int* __restrict__ src, const int* __restrict__ dst,
    const float* __restrict__ al, const float* __restrict__ ar,
    const unsigned* __restrict__ menc, float* __restrict__ denom, int E)
{
    int e = blockIdx.x * blockDim.x + threadIdx.x;
    if (e >= E) return;
    int s = src[e], d = dst[e];
    const float4 a_l = *(const float4*)(al + (size_t)s * 4);
    const float4 a_r = *(const float4*)(ar + (size_t)d * 4);
    float ev[4] = {a_r.x + a_l.x, a_r.y + a_l.y, a_r.z + a_l.z, a_r.w + a_l.w};
#pragma unroll
    for (int h = 0; h < 4; ++h) {
        float p = __expf(lrelu(ev[h]) - decF(menc[d*4 + h]));
        unsafeAtomicAdd(&denom[d*4 + h], p);
    }
}

// ---------------- edge pass 3: weighted scatter-aggregate ----------------
// one wave per edge, each lane owns 2 channels.
__global__ __launch_bounds__(256) void edge_aggr(
    const int* __restrict__ src, const int* __restrict__ dst,
    const float* __restrict__ al, const float* __restrict__ ar,
    const unsigned* __restrict__ menc, const float* __restrict__ denom,
    const float* __restrict__ xl, float* __restrict__ out, int E)
{
    int e = blockIdx.x * 4 + (threadIdx.x >> 6);
    if (e >= E) return;
    int lane = threadIdx.x & 63;
    int s = src[e], d = dst[e];
    int h = lane >> 4;  // ch = lane*2 -> head = ch/32
    float eh = lrelu(ar[(size_t)d*4 + h] + al[(size_t)s*4 + h]);
    float p = __expf(eh - decF(menc[d*4 + h]));
    float alpha = p / (denom[d*4 + h] + 1e-16f);
    float2 v = *(const float2*)(xl + (size_t)s * DIM + lane * 2);
    unsafeAtomicAdd(out + (size_t)d * DIM + lane*2,     v.x * alpha);
    unsafeAtomicAdd(out + (size_t)d * DIM + lane*2 + 1, v.y * alpha);
}

// ---------------- graph pooling (with relu on final h) ----------------
__global__ __launch_bounds__(256) void pool_nodes(
    const float* __restrict__ h, const int* __restrict__ batch,
    float* __restrict__ pooled, int n)
{
    int node = blockIdx.x * 4 + (threadIdx.x >> 6);
    if (node >= n) return;
    int lane = threadIdx.x & 63;
    int g = batch[node];
    float2 v = *(const float2*)(h + (size_t)node * DIM + lane * 2);
    unsafeAtomicAdd(pooled + (size_t)g * DIM + lane*2,     fmaxf(v.x, 0.f));
    unsafeAtomicAdd(pooled + (size_t)g * DIM + lane*2 + 1, fmaxf(v.y, 0.f));
}

// ---------------- final projection: out[g][j] = pooled[g] . proj_W[j] + b[j] ----
__global__ __launch_bounds__(256) void proj_out(
    const float* __restrict__ pooled, const float* __restrict__ W,
    const float* __restrict__ b, float* __restrict__ out, int G)
{
    int idx = blockIdx.x * blockDim.x + threadIdx.x;
    if (idx >= G * 32) return;
    int g = idx >> 5, j = idx & 31;
    const float* pr = pooled + (size_t)g * DIM;
    const float* wr = W + (size_t)j * DIM;
    float acc = 0.f;
#pragma unroll
    for (int k = 0; k < DIM; ++k) acc = fmaf(pr[k], wr[k], acc);
    out[idx] = acc + b[j];
}

extern "C" void kernel_launch(void* const* d_in, const int* in_sizes, int n_in,
                              void* d_out, int out_size, void* d_ws, size_t ws_size,
                              hipStream_t stream)
{
    const float* x      = (const float*)d_in[0];
    const int*   eidx   = (const int*)d_in[1];
    const int*   batch  = (const int*)d_in[2];
    const float* Ws     = (const float*)d_in[3];
    const float* bs     = (const float*)d_in[4];
    const float* attls  = (const float*)d_in[5];
    const float* attrs  = (const float*)d_in[6];
    const float* projW  = (const float*)d_in[7];
    const float* projb  = (const float*)d_in[8];

    const int N = in_sizes[0] / DIM;
    const int E = in_sizes[1] / 2;
    const int G = out_size / 32;
    const int* src = eidx;
    const int* dst = eidx + E;

    char* ws = (char*)d_ws;
    size_t o = 0;
    auto alloc = [&](size_t bytes) { char* p = ws + o; o += (bytes + 255) & ~255ull; return p; };
    float*    hA     = (float*)alloc((size_t)N * DIM * 4);
    float*    hB     = (float*)alloc((size_t)N * DIM * 4);
    float*    xl     = (float*)alloc((size_t)N * DIM * 4);
    float*    al     = (float*)alloc((size_t)N * 4 * 4);
    float*    ar     = (float*)alloc((size_t)N * 4 * 4);
    unsigned* menc   = (unsigned*)alloc((size_t)N * 4 * 4);
    float*    denom  = (float*)alloc((size_t)N * 4 * 4);
    float*    pooled = (float*)alloc((size_t)G * DIM * 4);

    const float* hin = x;
    float* houts[3] = {hA, hB, hA};
    for (int l = 0; l < 3; ++l) {
        float* hout = houts[l];
        hipMemsetAsync(menc,  0, (size_t)N * 4 * 4, stream);
        hipMemsetAsync(denom, 0, (size_t)N * 4 * 4, stream);
        hipMemsetAsync(hout,  0, (size_t)N * DIM * 4, stream);
        dim3 gb((N + 63) / 64);
        if (l == 0) gemm_nodes<false><<<gb, 256, 0, stream>>>(hin, Ws + (size_t)l*DIM*DIM, bs + l*DIM, xl, N);
        else        gemm_nodes<true ><<<gb, 256, 0, stream>>>(hin, Ws + (size_t)l*DIM*DIM, bs + l*DIM, xl, N);
        alpha_nodes<<<(N + 3) / 4, 256, 0, stream>>>(xl, attls + l*DIM, attrs + l*DIM, al, ar, N);
        edge_max<<<(E + 255) / 256, 256, 0, stream>>>(src, dst, al, ar, menc, E);
        edge_sum<<<(E + 255) / 256, 256, 0, stream>>>(src, dst, al, ar, menc, denom, E);
        edge_aggr<<<(E + 3) / 4, 256, 0, stream>>>(src, dst, al, ar, menc, denom, xl, hout, E);
        hin = hout;
    }
    hipMemsetAsync(pooled, 0, (size_t)G * DIM * 4, stream);
    pool_nodes<<<(N + 3) / 4, 256, 0, stream>>>(hA, batch, pooled, N);
    proj_out<<<(G * 32 + 255) / 256, 256, 0, stream>>>(pooled, projW, projb, (float*)d_out, G);
}

// Round 2
// 664.868 us; speedup vs baseline: 4.7078x; 4.7078x over previous
//
#include <hip/hip_runtime.h>
#include <hip/hip_bf16.h>

#define NHEADS 4
#define DIM 128
#define NEG_SLOPE 0.2f

__device__ __forceinline__ float lrelu(float x) { return x > 0.f ? x : NEG_SLOPE * x; }

// ---------------- GEMM: out[n][j] = sum_k relu?(in[n][k]) * W[j][k] + b[j] -------------
template<bool RELU_IN>
__global__ __launch_bounds__(256) void gemm_nodes(
    const float* __restrict__ in, const float* __restrict__ W,
    const float* __restrict__ bias, float* __restrict__ out, int n)
{
    __shared__ float As[32][68];
    __shared__ float Bs[32][132];
    const int tid = threadIdx.x;
    const int ty = tid >> 4, tx = tid & 15;
    const int n0 = blockIdx.x * 64;

    float acc[4][8];
#pragma unroll
    for (int i = 0; i < 4; ++i)
#pragma unroll
        for (int j = 0; j < 8; ++j) acc[i][j] = 0.f;

    const int arow = tid >> 2, ak0 = (tid & 3) * 8;
    const int bj = tid >> 1, bk0 = (tid & 1) * 16;

    for (int k0 = 0; k0 < DIM; k0 += 32) {
        float v[8];
        if (n0 + arow < n) {
            const float* p = in + (size_t)(n0 + arow) * DIM + k0 + ak0;
            float4 x0 = *(const float4*)p;
            float4 x1 = *(const float4*)(p + 4);
            v[0]=x0.x; v[1]=x0.y; v[2]=x0.z; v[3]=x0.w;
            v[4]=x1.x; v[5]=x1.y; v[6]=x1.z; v[7]=x1.w;
            if (RELU_IN) {
#pragma unroll
                for (int i = 0; i < 8; ++i) v[i] = fmaxf(v[i], 0.f);
            }
        } else {
#pragma unroll
            for (int i = 0; i < 8; ++i) v[i] = 0.f;
        }
#pragma unroll
        for (int i = 0; i < 8; ++i) As[ak0 + i][arow] = v[i];

        {
            const float* p = W + (size_t)bj * DIM + k0 + bk0;
#pragma unroll
            for (int q = 0; q < 4; ++q) {
                float4 x = *(const float4*)(p + q * 4);
                Bs[bk0 + q*4 + 0][bj] = x.x; Bs[bk0 + q*4 + 1][bj] = x.y;
                Bs[bk0 + q*4 + 2][bj] = x.z; Bs[bk0 + q*4 + 3][bj] = x.w;
            }
        }
        __syncthreads();
#pragma unroll
        for (int kk = 0; kk < 32; ++kk) {
            float4 a  = *(const float4*)&As[kk][ty * 4];
            float4 b0 = *(const float4*)&Bs[kk][tx * 4];
            float4 b1 = *(const float4*)&Bs[kk][64 + tx * 4];
            float av[4] = {a.x, a.y, a.z, a.w};
            float bv[8] = {b0.x, b0.y, b0.z, b0.w, b1.x, b1.y, b1.z, b1.w};
#pragma unroll
            for (int i = 0; i < 4; ++i)
#pragma unroll
                for (int j = 0; j < 8; ++j)
                    acc[i][j] = fmaf(av[i], bv[j], acc[i][j]);
        }
        __syncthreads();
    }
#pragma unroll
    for (int i = 0; i < 4; ++i) {
        int row = n0 + ty * 4 + i;
        if (row < n) {
            float* po = out + (size_t)row * DIM;
#pragma unroll
            for (int j = 0; j < 4; ++j) {
                po[tx*4 + j]      = acc[i][j]     + bias[tx*4 + j];
                po[64 + tx*4 + j] = acc[i][j + 4] + bias[64 + tx*4 + j];
            }
        }
    }
}

// ---------------- per-node attention coefficients ----------------
__global__ __launch_bounds__(256) void alpha_nodes(
    const float* __restrict__ xl, const float* __restrict__ attl,
    const float* __restrict__ attr, float* __restrict__ al,
    float* __restrict__ ar, int n)
{
    int node = blockIdx.x * 4 + (threadIdx.x >> 6);
    if (node >= n) return;
    int lane = threadIdx.x & 63;
    float v0 = xl[(size_t)node * DIM + lane];
    float v1 = xl[(size_t)node * DIM + 64 + lane];
    float l0 = v0 * attl[lane],      r0 = v0 * attr[lane];
    float l1 = v1 * attl[64 + lane], r1 = v1 * attr[64 + lane];
#pragma unroll
    for (int off = 16; off >= 1; off >>= 1) {
        l0 += __shfl_xor(l0, off); r0 += __shfl_xor(r0, off);
        l1 += __shfl_xor(l1, off); r1 += __shfl_xor(r1, off);
    }
    if ((lane & 31) == 0) {
        int h = lane >> 5;
        al[node*4 + h]     = l0; ar[node*4 + h]     = r0;
        al[node*4 + 2 + h] = l1; ar[node*4 + 2 + h] = r1;
    }
}

// ---------------- CSR build ----------------
__global__ __launch_bounds__(256) void deg_count(
    const int* __restrict__ dst, int* __restrict__ deg, int E)
{
    int e = blockIdx.x * blockDim.x + threadIdx.x;
    if (e < E) atomicAdd(&deg[dst[e]], 1);
}

// 1024 elements per block: per-thread 4-elem prefix + LDS Hillis-Steele over 256 totals
__global__ __launch_bounds__(256) void scan_blocks(
    const int* __restrict__ deg, int* __restrict__ rowptr,
    int* __restrict__ partials, int n)
{
    __shared__ int tot[256];
    int t = threadIdx.x;
    int base = blockIdx.x * 1024 + t * 4;
    int v[4];
#pragma unroll
    for (int j = 0; j < 4; ++j) v[j] = (base + j < n) ? deg[base + j] : 0;
    int p1 = v[0], p2 = p1 + v[1], p3 = p2 + v[2], sum4 = p3 + v[3];
    tot[t] = sum4;
    __syncthreads();
    int val = sum4;
    for (int off = 1; off < 256; off <<= 1) {
        int other = (t >= off) ? tot[t - off] : 0;
        __syncthreads();
        val += other;
        tot[t] = val;
        __syncthreads();
    }
    int excl = val - sum4;
    if (base < n)     rowptr[base]     = excl;
    if (base+1 < n)   rowptr[base+1]   = excl + p1;
    if (base+2 < n)   rowptr[base+2]   = excl + p2;
    if (base+3 < n)   rowptr[base+3]   = excl + p3;
    if (t == 255) partials[blockIdx.x] = val;
}

// single block; nb <= 256
__global__ __launch_bounds__(256) void scan_partials(
    int* __restrict__ partials, int nb, int* __restrict__ rowptr, int n)
{
    __shared__ int tot[256];
    int t = threadIdx.x;
    int v = (t < nb) ? partials[t] : 0;
    tot[t] = v;
    __syncthreads();
    int val = v;
    for (int off = 1; off < 256; off <<= 1) {
        int other = (t >= off) ? tot[t - off] : 0;
        __syncthreads();
        val += other;
        tot[t] = val;
        __syncthreads();
    }
    if (t < nb) partials[t] = val - v;
    if (t == 255) rowptr[n] = val;   // total = E
}

__global__ __launch_bounds__(256) void add_offsets(
    int* __restrict__ rowptr, int* __restrict__ wpos,
    const int* __restrict__ partials, int n)
{
    int base = blockIdx.x * 1024 + threadIdx.x * 4;
    int off = partials[blockIdx.x];
#pragma unroll
    for (int j = 0; j < 4; ++j) {
        int i = base + j;
        if (i < n) { int r = rowptr[i] + off; rowptr[i] = r; wpos[i] = r; }
    }
}

__global__ __launch_bounds__(256) void scatter_edges(
    const int* __restrict__ src, const int* __restrict__ dst,
    int* __restrict__ wpos, int* __restrict__ col, int E)
{
    int e = blockIdx.x * blockDim.x + threadIdx.x;
    if (e >= E) return;
    int p = atomicAdd(&wpos[dst[e]], 1);
    col[p] = src[e];
}

// ---------------- fused per-node softmax + aggregate (gather, no atomics) -----
// one wave per dst node; lane owns channels [2*lane, 2*lane+1]
__global__ __launch_bounds__(256) void gat_aggregate(
    const int* __restrict__ rowptr, const int* __restrict__ col,
    const float* __restrict__ al, const float* __restrict__ ar,
    const float* __restrict__ xl, float* __restrict__ out, int n)
{
    int node = blockIdx.x * 4 + (threadIdx.x >> 6);
    if (node >= n) return;
    int lane = threadIdx.x & 63;
    int r0 = rowptr[node], r1 = rowptr[node + 1];
    int deg = r1 - r0;
    float4 arv = *(const float4*)(ar + (size_t)node * 4);

    // Phase A: per-head max over in-edges
    float m0 = -1e30f, m1 = -1e30f, m2 = -1e30f, m3 = -1e30f;
    for (int i = lane; i < deg; i += 64) {
        int s = col[r0 + i];
        float4 a = *(const float4*)(al + (size_t)s * 4);
        m0 = fmaxf(m0, lrelu(arv.x + a.x));
        m1 = fmaxf(m1, lrelu(arv.y + a.y));
        m2 = fmaxf(m2, lrelu(arv.z + a.z));
        m3 = fmaxf(m3, lrelu(arv.w + a.w));
    }
#pragma unroll
    for (int off = 32; off >= 1; off >>= 1) {
        m0 = fmaxf(m0, __shfl_xor(m0, off));
        m1 = fmaxf(m1, __shfl_xor(m1, off));
        m2 = fmaxf(m2, __shfl_xor(m2, off));
        m3 = fmaxf(m3, __shfl_xor(m3, off));
    }
    // Phase B: per-head exp-sum
    float s0 = 0.f, s1 = 0.f, s2 = 0.f, s3 = 0.f;
    for (int i = lane; i < deg; i += 64) {
        int s = col[r0 + i];
        float4 a = *(const float4*)(al + (size_t)s * 4);
        s0 += __expf(lrelu(arv.x + a.x) - m0);
        s1 += __expf(lrelu(arv.y + a.y) - m1);
        s2 += __expf(lrelu(arv.z + a.z) - m2);
        s3 += __expf(lrelu(arv.w + a.w) - m3);
    }
#pragma unroll
    for (int off = 32; off >= 1; off >>= 1) {
        s0 += __shfl_xor(s0, off);
        s1 += __shfl_xor(s1, off);
        s2 += __shfl_xor(s2, off);
        s3 += __shfl_xor(s3, off);
    }
    // Phase C: weighted gather-accumulate; lane owns 2 channels of head h
    int h = lane >> 4;
    float mh   = (h == 0) ? m0 : (h == 1) ? m1 : (h == 2) ? m2 : m3;
    float sh   = (h == 0) ? s0 : (h == 1) ? s1 : (h == 2) ? s2 : s3;
    float arh  = (h == 0) ? arv.x : (h == 1) ? arv.y : (h == 2) ? arv.z : arv.w;
    float invh = 1.f / (sh + 1e-16f);
    float acc0 = 0.f, acc1 = 0.f;
    for (int i = 0; i < deg; ++i) {
        int s = col[r0 + i];
        float alh = al[(size_t)s * 4 + h];
        float w = __expf(lrelu(arh + alh) - mh) * invh;
        float2 v = *(const float2*)(xl + (size_t)s * DIM + lane * 2);
        acc0 = fmaf(w, v.x, acc0);
        acc1 = fmaf(w, v.y, acc1);
    }
    *(float2*)(out + (size_t)node * DIM + lane * 2) = make_float2(acc0, acc1);
}

// ---------------- graph pooling (relu on final h) ----------------
__global__ __launch_bounds__(256) void pool_nodes(
    const float* __restrict__ h, const int* __restrict__ batch,
    float* __restrict__ pooled, int n)
{
    int node = blockIdx.x * 4 + (threadIdx.x >> 6);
    if (node >= n) return;
    int lane = threadIdx.x & 63;
    int g = batch[node];
    float2 v = *(const float2*)(h + (size_t)node * DIM + lane * 2);
    unsafeAtomicAdd(pooled + (size_t)g * DIM + lane*2,     fmaxf(v.x, 0.f));
    unsafeAtomicAdd(pooled + (size_t)g * DIM + lane*2 + 1, fmaxf(v.y, 0.f));
}

// ---------------- final projection ----------------
__global__ __launch_bounds__(256) void proj_out(
    const float* __restrict__ pooled, const float* __restrict__ W,
    const float* __restrict__ b, float* __restrict__ out, int G)
{
    int idx = blockIdx.x * blockDim.x + threadIdx.x;
    if (idx >= G * 32) return;
    int g = idx >> 5, j = idx & 31;
    const float* pr = pooled + (size_t)g * DIM;
    const float* wr = W + (size_t)j * DIM;
    float acc = 0.f;
#pragma unroll
    for (int k = 0; k < DIM; ++k) acc = fmaf(pr[k], wr[k], acc);
    out[idx] = acc + b[j];
}

extern "C" void kernel_launch(void* const* d_in, const int* in_sizes, int n_in,
                              void* d_out, int out_size, void* d_ws, size_t ws_size,
                              hipStream_t stream)
{
    const float* x      = (const float*)d_in[0];
    const int*   eidx   = (const int*)d_in[1];
    const int*   batch  = (const int*)d_in[2];
    const float* Ws     = (const float*)d_in[3];
    const float* bs     = (const float*)d_in[4];
    const float* attls  = (const float*)d_in[5];
    const float* attrs  = (const float*)d_in[6];
    const float* projW  = (const float*)d_in[7];
    const float* projb  = (const float*)d_in[8];

    const int N = in_sizes[0] / DIM;
    const int E = in_sizes[1] / 2;
    const int G = out_size / 32;
    const int* src = eidx;
    const int* dst = eidx + E;

    char* ws = (char*)d_ws;
    size_t o = 0;
    auto alloc = [&](size_t bytes) { char* p = ws + o; o += (bytes + 255) & ~255ull; return p; };
    float* hA     = (float*)alloc((size_t)N * DIM * 4);
    float* hB     = (float*)alloc((size_t)N * DIM * 4);
    float* xl     = (float*)alloc((size_t)N * DIM * 4);
    float* al     = (float*)alloc((size_t)N * 4 * 4);
    float* ar     = (float*)alloc((size_t)N * 4 * 4);
    int*   rowptr = (int*)alloc((size_t)(N + 1) * 4);
    int*   wpos   = (int*)alloc((size_t)N * 4);
    int*   deg    = (int*)alloc((size_t)N * 4);
    int*   colv   = (int*)alloc((size_t)E * 4);
    int*   parts  = (int*)alloc(256 * 4);
    float* pooled = (float*)alloc((size_t)G * DIM * 4);

    // ---- CSR build (once; edge structure shared by all 3 layers) ----
    const int nb = (N + 1023) / 1024;
    hipMemsetAsync(deg, 0, (size_t)N * 4, stream);
    deg_count<<<(E + 255) / 256, 256, 0, stream>>>(dst, deg, E);
    scan_blocks<<<nb, 256, 0, stream>>>(deg, rowptr, parts, N);
    scan_partials<<<1, 256, 0, stream>>>(parts, nb, rowptr, N);
    add_offsets<<<nb, 256, 0, stream>>>(rowptr, wpos, parts, N);
    scatter_edges<<<(E + 255) / 256, 256, 0, stream>>>(src, dst, wpos, colv, E);

    // ---- 3 GAT layers ----
    const float* hin = x;
    float* houts[3] = {hA, hB, hA};
    for (int l = 0; l < 3; ++l) {
        float* hout = houts[l];
        dim3 gb((N + 63) / 64);
        if (l == 0) gemm_nodes<false><<<gb, 256, 0, stream>>>(hin, Ws + (size_t)l*DIM*DIM, bs + l*DIM, xl, N);
        else        gemm_nodes<true ><<<gb, 256, 0, stream>>>(hin, Ws + (size_t)l*DIM*DIM, bs + l*DIM, xl, N);
        alpha_nodes<<<(N + 3) / 4, 256, 0, stream>>>(xl, attls + l*DIM, attrs + l*DIM, al, ar, N);
        gat_aggregate<<<(N + 3) / 4, 256, 0, stream>>>(rowptr, colv, al, ar, xl, hout, N);
        hin = hout;
    }

    // ---- pool + projection ----
    hipMemsetAsync(pooled, 0, (size_t)G * DIM * 4, stream);
    pool_nodes<<<(N + 3) / 4, 256, 0, stream>>>(hA, batch, pooled, N);
    proj_out<<<(G * 32 + 255) / 256, 256, 0, stream>>>(pooled, projW, projb, (float*)d_out, G);
}

// Round 3
// 570.639 us; speedup vs baseline: 5.4851x; 1.1651x over previous
//
#include <hip/hip_runtime.h>
#include <hip/hip_bf16.h>

#define NHEADS 4
#define DIM 128
#define NEG_SLOPE 0.2f
#define POOL_CHUNK 256

__device__ __forceinline__ float lrelu(float x) { return x > 0.f ? x : NEG_SLOPE * x; }

// ---------------- GEMM: out[n][j] = sum_k relu?(in[n][k]) * W[j][k] + b[j] -------------
template<bool RELU_IN>
__global__ __launch_bounds__(256) void gemm_nodes(
    const float* __restrict__ in, const float* __restrict__ W,
    const float* __restrict__ bias, float* __restrict__ out, int n)
{
    __shared__ float As[32][68];
    __shared__ float Bs[32][132];
    const int tid = threadIdx.x;
    const int ty = tid >> 4, tx = tid & 15;
    const int n0 = blockIdx.x * 64;

    float acc[4][8];
#pragma unroll
    for (int i = 0; i < 4; ++i)
#pragma unroll
        for (int j = 0; j < 8; ++j) acc[i][j] = 0.f;

    const int arow = tid >> 2, ak0 = (tid & 3) * 8;
    const int bj = tid >> 1, bk0 = (tid & 1) * 16;

    for (int k0 = 0; k0 < DIM; k0 += 32) {
        float v[8];
        if (n0 + arow < n) {
            const float* p = in + (size_t)(n0 + arow) * DIM + k0 + ak0;
            float4 x0 = *(const float4*)p;
            float4 x1 = *(const float4*)(p + 4);
            v[0]=x0.x; v[1]=x0.y; v[2]=x0.z; v[3]=x0.w;
            v[4]=x1.x; v[5]=x1.y; v[6]=x1.z; v[7]=x1.w;
            if (RELU_IN) {
#pragma unroll
                for (int i = 0; i < 8; ++i) v[i] = fmaxf(v[i], 0.f);
            }
        } else {
#pragma unroll
            for (int i = 0; i < 8; ++i) v[i] = 0.f;
        }
#pragma unroll
        for (int i = 0; i < 8; ++i) As[ak0 + i][arow] = v[i];

        {
            const float* p = W + (size_t)bj * DIM + k0 + bk0;
#pragma unroll
            for (int q = 0; q < 4; ++q) {
                float4 x = *(const float4*)(p + q * 4);
                Bs[bk0 + q*4 + 0][bj] = x.x; Bs[bk0 + q*4 + 1][bj] = x.y;
                Bs[bk0 + q*4 + 2][bj] = x.z; Bs[bk0 + q*4 + 3][bj] = x.w;
            }
        }
        __syncthreads();
#pragma unroll
        for (int kk = 0; kk < 32; ++kk) {
            float4 a  = *(const float4*)&As[kk][ty * 4];
            float4 b0 = *(const float4*)&Bs[kk][tx * 4];
            float4 b1 = *(const float4*)&Bs[kk][64 + tx * 4];
            float av[4] = {a.x, a.y, a.z, a.w};
            float bv[8] = {b0.x, b0.y, b0.z, b0.w, b1.x, b1.y, b1.z, b1.w};
#pragma unroll
            for (int i = 0; i < 4; ++i)
#pragma unroll
                for (int j = 0; j < 8; ++j)
                    acc[i][j] = fmaf(av[i], bv[j], acc[i][j]);
        }
        __syncthreads();
    }
#pragma unroll
    for (int i = 0; i < 4; ++i) {
        int row = n0 + ty * 4 + i;
        if (row < n) {
            float* po = out + (size_t)row * DIM;
#pragma unroll
            for (int j = 0; j < 4; ++j) {
                po[tx*4 + j]      = acc[i][j]     + bias[tx*4 + j];
                po[64 + tx*4 + j] = acc[i][j + 4] + bias[64 + tx*4 + j];
            }
        }
    }
}

// ---------------- per-node attention coefficients ----------------
__global__ __launch_bounds__(256) void alpha_nodes(
    const float* __restrict__ xl, const float* __restrict__ attl,
    const float* __restrict__ attr, float* __restrict__ al,
    float* __restrict__ ar, int n)
{
    int node = blockIdx.x * 4 + (threadIdx.x >> 6);
    if (node >= n) return;
    int lane = threadIdx.x & 63;
    float v0 = xl[(size_t)node * DIM + lane];
    float v1 = xl[(size_t)node * DIM + 64 + lane];
    float l0 = v0 * attl[lane],      r0 = v0 * attr[lane];
    float l1 = v1 * attl[64 + lane], r1 = v1 * attr[64 + lane];
#pragma unroll
    for (int off = 16; off >= 1; off >>= 1) {
        l0 += __shfl_xor(l0, off); r0 += __shfl_xor(r0, off);
        l1 += __shfl_xor(l1, off); r1 += __shfl_xor(r1, off);
    }
    if ((lane & 31) == 0) {
        int h = lane >> 5;
        al[node*4 + h]     = l0; ar[node*4 + h]     = r0;
        al[node*4 + 2 + h] = l1; ar[node*4 + 2 + h] = r1;
    }
}

// ---------------- CSR build ----------------
__global__ __launch_bounds__(256) void deg_count(
    const int* __restrict__ dst, int* __restrict__ deg, int E)
{
    int e = blockIdx.x * blockDim.x + threadIdx.x;
    if (e < E) atomicAdd(&deg[dst[e]], 1);
}

__global__ __launch_bounds__(256) void scan_blocks(
    const int* __restrict__ deg, int* __restrict__ rowptr,
    int* __restrict__ partials, int n)
{
    __shared__ int tot[256];
    int t = threadIdx.x;
    int base = blockIdx.x * 1024 + t * 4;
    int v[4];
#pragma unroll
    for (int j = 0; j < 4; ++j) v[j] = (base + j < n) ? deg[base + j] : 0;
    int p1 = v[0], p2 = p1 + v[1], p3 = p2 + v[2], sum4 = p3 + v[3];
    tot[t] = sum4;
    __syncthreads();
    int val = sum4;
    for (int off = 1; off < 256; off <<= 1) {
        int other = (t >= off) ? tot[t - off] : 0;
        __syncthreads();
        val += other;
        tot[t] = val;
        __syncthreads();
    }
    int excl = val - sum4;
    if (base < n)     rowptr[base]     = excl;
    if (base+1 < n)   rowptr[base+1]   = excl + p1;
    if (base+2 < n)   rowptr[base+2]   = excl + p2;
    if (base+3 < n)   rowptr[base+3]   = excl + p3;
    if (t == 255) partials[blockIdx.x] = val;
}

__global__ __launch_bounds__(256) void scan_partials(
    int* __restrict__ partials, int nb, int* __restrict__ rowptr, int n)
{
    __shared__ int tot[256];
    int t = threadIdx.x;
    int v = (t < nb) ? partials[t] : 0;
    tot[t] = v;
    __syncthreads();
    int val = v;
    for (int off = 1; off < 256; off <<= 1) {
        int other = (t >= off) ? tot[t - off] : 0;
        __syncthreads();
        val += other;
        tot[t] = val;
        __syncthreads();
    }
    if (t < nb) partials[t] = val - v;
    if (t == 255) rowptr[n] = val;
}

__global__ __launch_bounds__(256) void add_offsets(
    int* __restrict__ rowptr, int* __restrict__ wpos,
    const int* __restrict__ partials, int n)
{
    int base = blockIdx.x * 1024 + threadIdx.x * 4;
    int off = partials[blockIdx.x];
#pragma unroll
    for (int j = 0; j < 4; ++j) {
        int i = base + j;
        if (i < n) { int r = rowptr[i] + off; rowptr[i] = r; wpos[i] = r; }
    }
}

__global__ __launch_bounds__(256) void scatter_edges(
    const int* __restrict__ src, const int* __restrict__ dst,
    int* __restrict__ wpos, int* __restrict__ col, int E)
{
    int e = blockIdx.x * blockDim.x + threadIdx.x;
    if (e >= E) return;
    int p = atomicAdd(&wpos[dst[e]], 1);
    col[p] = src[e];
}

// ---------------- fused per-node softmax + aggregate (gather, no atomics) -----
__global__ __launch_bounds__(256) void gat_aggregate(
    const int* __restrict__ rowptr, const int* __restrict__ col,
    const float* __restrict__ al, const float* __restrict__ ar,
    const float* __restrict__ xl, float* __restrict__ out, int n)
{
    int node = blockIdx.x * 4 + (threadIdx.x >> 6);
    if (node >= n) return;
    int lane = threadIdx.x & 63;
    int r0 = rowptr[node], r1 = rowptr[node + 1];
    int deg = r1 - r0;
    float4 arv = *(const float4*)(ar + (size_t)node * 4);

    float m0 = -1e30f, m1 = -1e30f, m2 = -1e30f, m3 = -1e30f;
    for (int i = lane; i < deg; i += 64) {
        int s = col[r0 + i];
        float4 a = *(const float4*)(al + (size_t)s * 4);
        m0 = fmaxf(m0, lrelu(arv.x + a.x));
        m1 = fmaxf(m1, lrelu(arv.y + a.y));
        m2 = fmaxf(m2, lrelu(arv.z + a.z));
        m3 = fmaxf(m3, lrelu(arv.w + a.w));
    }
#pragma unroll
    for (int off = 32; off >= 1; off >>= 1) {
        m0 = fmaxf(m0, __shfl_xor(m0, off));
        m1 = fmaxf(m1, __shfl_xor(m1, off));
        m2 = fmaxf(m2, __shfl_xor(m2, off));
        m3 = fmaxf(m3, __shfl_xor(m3, off));
    }
    float s0 = 0.f, s1 = 0.f, s2 = 0.f, s3 = 0.f;
    for (int i = lane; i < deg; i += 64) {
        int s = col[r0 + i];
        float4 a = *(const float4*)(al + (size_t)s * 4);
        s0 += __expf(lrelu(arv.x + a.x) - m0);
        s1 += __expf(lrelu(arv.y + a.y) - m1);
        s2 += __expf(lrelu(arv.z + a.z) - m2);
        s3 += __expf(lrelu(arv.w + a.w) - m3);
    }
#pragma unroll
    for (int off = 32; off >= 1; off >>= 1) {
        s0 += __shfl_xor(s0, off);
        s1 += __shfl_xor(s1, off);
        s2 += __shfl_xor(s2, off);
        s3 += __shfl_xor(s3, off);
    }
    int h = lane >> 4;
    float mh   = (h == 0) ? m0 : (h == 1) ? m1 : (h == 2) ? m2 : m3;
    float sh   = (h == 0) ? s0 : (h == 1) ? s1 : (h == 2) ? s2 : s3;
    float arh  = (h == 0) ? arv.x : (h == 1) ? arv.y : (h == 2) ? arv.z : arv.w;
    float invh = 1.f / (sh + 1e-16f);
    float acc0 = 0.f, acc1 = 0.f;
    for (int i = 0; i < deg; ++i) {
        int s = col[r0 + i];
        float alh = al[(size_t)s * 4 + h];
        float w = __expf(lrelu(arh + alh) - mh) * invh;
        float2 v = *(const float2*)(xl + (size_t)s * DIM + lane * 2);
        acc0 = fmaf(w, v.x, acc0);
        acc1 = fmaf(w, v.y, acc1);
    }
    *(float2*)(out + (size_t)node * DIM + lane * 2) = make_float2(acc0, acc1);
}

// ---------------- graph pooling: segmented (batch is sorted) ----------------
// one wave covers all 128 channels (lane owns 2); running per-graph partial,
// flush via atomic only at graph boundaries.
__global__ __launch_bounds__(256) void pool_nodes_seg(
    const float* __restrict__ h, const int* __restrict__ batch,
    float* __restrict__ pooled, int n)
{
    int wid = threadIdx.x >> 6;
    int lane = threadIdx.x & 63;
    int start = blockIdx.x * POOL_CHUNK;
    int end = min(start + POOL_CHUNK, n);
    float a0 = 0.f, a1 = 0.f;
    int curg = -1;
    for (int node = start + wid; node < end; node += 4) {
        int g = batch[node];
        if (g != curg) {
            if (curg >= 0) {
                unsafeAtomicAdd(pooled + (size_t)curg * DIM + lane*2,     a0);
                unsafeAtomicAdd(pooled + (size_t)curg * DIM + lane*2 + 1, a1);
            }
            curg = g; a0 = 0.f; a1 = 0.f;
        }
        float2 v = *(const float2*)(h + (size_t)node * DIM + lane * 2);
        a0 += fmaxf(v.x, 0.f);
        a1 += fmaxf(v.y, 0.f);
    }
    if (curg >= 0) {
        unsafeAtomicAdd(pooled + (size_t)curg * DIM + lane*2,     a0);
        unsafeAtomicAdd(pooled + (size_t)curg * DIM + lane*2 + 1, a1);
    }
}

// ---------------- final projection ----------------
__global__ __launch_bounds__(256) void proj_out(
    const float* __restrict__ pooled, const float* __restrict__ W,
    const float* __restrict__ b, float* __restrict__ out, int G)
{
    int idx = blockIdx.x * blockDim.x + threadIdx.x;
    if (idx >= G * 32) return;
    int g = idx >> 5, j = idx & 31;
    const float* pr = pooled + (size_t)g * DIM;
    const float* wr = W + (size_t)j * DIM;
    float acc = 0.f;
#pragma unroll
    for (int k = 0; k < DIM; ++k) acc = fmaf(pr[k], wr[k], acc);
    out[idx] = acc + b[j];
}

extern "C" void kernel_launch(void* const* d_in, const int* in_sizes, int n_in,
                              void* d_out, int out_size, void* d_ws, size_t ws_size,
                              hipStream_t stream)
{
    const float* x      = (const float*)d_in[0];
    const int*   eidx   = (const int*)d_in[1];
    const int*   batch  = (const int*)d_in[2];
    const float* Ws     = (const float*)d_in[3];
    const float* bs     = (const float*)d_in[4];
    const float* attls  = (const float*)d_in[5];
    const float* attrs  = (const float*)d_in[6];
    const float* projW  = (const float*)d_in[7];
    const float* projb  = (const float*)d_in[8];

    const int N = in_sizes[0] / DIM;
    const int E = in_sizes[1] / 2;
    const int G = out_size / 32;
    const int* src = eidx;
    const int* dst = eidx + E;

    char* ws = (char*)d_ws;
    size_t o = 0;
    auto alloc = [&](size_t bytes) { char* p = ws + o; o += (bytes + 255) & ~255ull; return p; };
    float* hA     = (float*)alloc((size_t)N * DIM * 4);
    float* hB     = (float*)alloc((size_t)N * DIM * 4);
    float* xl     = (float*)alloc((size_t)N * DIM * 4);
    float* al     = (float*)alloc((size_t)N * 4 * 4);
    float* ar     = (float*)alloc((size_t)N * 4 * 4);
    int*   rowptr = (int*)alloc((size_t)(N + 1) * 4);
    int*   wpos   = (int*)alloc((size_t)N * 4);
    int*   deg    = (int*)alloc((size_t)N * 4);
    int*   colv   = (int*)alloc((size_t)E * 4);
    int*   parts  = (int*)alloc(256 * 4);
    float* pooled = (float*)alloc((size_t)G * DIM * 4);

    // ---- CSR build (once; edge structure shared by all 3 layers) ----
    const int nb = (N + 1023) / 1024;
    hipMemsetAsync(deg, 0, (size_t)N * 4, stream);
    deg_count<<<(E + 255) / 256, 256, 0, stream>>>(dst, deg, E);
    scan_blocks<<<nb, 256, 0, stream>>>(deg, rowptr, parts, N);
    scan_partials<<<1, 256, 0, stream>>>(parts, nb, rowptr, N);
    add_offsets<<<nb, 256, 0, stream>>>(rowptr, wpos, parts, N);
    scatter_edges<<<(E + 255) / 256, 256, 0, stream>>>(src, dst, wpos, colv, E);

    // ---- 3 GAT layers ----
    const float* hin = x;
    float* houts[3] = {hA, hB, hA};
    for (int l = 0; l < 3; ++l) {
        float* hout = houts[l];
        dim3 gb((N + 63) / 64);
        if (l == 0) gemm_nodes<false><<<gb, 256, 0, stream>>>(hin, Ws + (size_t)l*DIM*DIM, bs + l*DIM, xl, N);
        else        gemm_nodes<true ><<<gb, 256, 0, stream>>>(hin, Ws + (size_t)l*DIM*DIM, bs + l*DIM, xl, N);
        alpha_nodes<<<(N + 3) / 4, 256, 0, stream>>>(xl, attls + l*DIM, attrs + l*DIM, al, ar, N);
        gat_aggregate<<<(N + 3) / 4, 256, 0, stream>>>(rowptr, colv, al, ar, xl, hout, N);
        hin = hout;
    }

    // ---- pool + projection ----
    hipMemsetAsync(pooled, 0, (size_t)G * DIM * 4, stream);
    pool_nodes_seg<<<(N + POOL_CHUNK - 1) / POOL_CHUNK, 256, 0, stream>>>(hA, batch, pooled, N);
    proj_out<<<(G * 32 + 255) / 256, 256, 0, stream>>>(pooled, projW, projb, (float*)d_out, G);
}

// Round 4
// 450.602 us; speedup vs baseline: 6.9463x; 1.2664x over previous
//
#include <hip/hip_runtime.h>
#include <hip/hip_bf16.h>

#define NHEADS 4
#define DIM 128
#define NEG_SLOPE 0.2f
#define POOL_CHUNK 256

__device__ __forceinline__ float lrelu(float x) { return x > 0.f ? x : NEG_SLOPE * x; }
__device__ __forceinline__ float4 lrelu4(float4 a, float4 b) {
    return make_float4(lrelu(a.x + b.x), lrelu(a.y + b.y), lrelu(a.z + b.z), lrelu(a.w + b.w));
}
__device__ __forceinline__ float4 redmax4(float4 v) {
#pragma unroll
    for (int off = 32; off >= 1; off >>= 1) {
        v.x = fmaxf(v.x, __shfl_xor(v.x, off));
        v.y = fmaxf(v.y, __shfl_xor(v.y, off));
        v.z = fmaxf(v.z, __shfl_xor(v.z, off));
        v.w = fmaxf(v.w, __shfl_xor(v.w, off));
    }
    return v;
}
__device__ __forceinline__ float4 redsum4(float4 v) {
#pragma unroll
    for (int off = 32; off >= 1; off >>= 1) {
        v.x += __shfl_xor(v.x, off);
        v.y += __shfl_xor(v.y, off);
        v.z += __shfl_xor(v.z, off);
        v.w += __shfl_xor(v.w, off);
    }
    return v;
}

// ---------------- GEMM: out[n][j] = sum_k relu?(in[n][k]) * W[j][k] + b[j] -------------
template<bool RELU_IN>
__global__ __launch_bounds__(256) void gemm_nodes(
    const float* __restrict__ in, const float* __restrict__ W,
    const float* __restrict__ bias, float* __restrict__ out, int n)
{
    __shared__ float As[32][68];
    __shared__ float Bs[32][132];
    const int tid = threadIdx.x;
    const int ty = tid >> 4, tx = tid & 15;
    const int n0 = blockIdx.x * 64;

    float acc[4][8];
#pragma unroll
    for (int i = 0; i < 4; ++i)
#pragma unroll
        for (int j = 0; j < 8; ++j) acc[i][j] = 0.f;

    const int arow = tid >> 2, ak0 = (tid & 3) * 8;
    const int bj = tid >> 1, bk0 = (tid & 1) * 16;

    for (int k0 = 0; k0 < DIM; k0 += 32) {
        float v[8];
        if (n0 + arow < n) {
            const float* p = in + (size_t)(n0 + arow) * DIM + k0 + ak0;
            float4 x0 = *(const float4*)p;
            float4 x1 = *(const float4*)(p + 4);
            v[0]=x0.x; v[1]=x0.y; v[2]=x0.z; v[3]=x0.w;
            v[4]=x1.x; v[5]=x1.y; v[6]=x1.z; v[7]=x1.w;
            if (RELU_IN) {
#pragma unroll
                for (int i = 0; i < 8; ++i) v[i] = fmaxf(v[i], 0.f);
            }
        } else {
#pragma unroll
            for (int i = 0; i < 8; ++i) v[i] = 0.f;
        }
#pragma unroll
        for (int i = 0; i < 8; ++i) As[ak0 + i][arow] = v[i];

        {
            const float* p = W + (size_t)bj * DIM + k0 + bk0;
#pragma unroll
            for (int q = 0; q < 4; ++q) {
                float4 x = *(const float4*)(p + q * 4);
                Bs[bk0 + q*4 + 0][bj] = x.x; Bs[bk0 + q*4 + 1][bj] = x.y;
                Bs[bk0 + q*4 + 2][bj] = x.z; Bs[bk0 + q*4 + 3][bj] = x.w;
            }
        }
        __syncthreads();
#pragma unroll
        for (int kk = 0; kk < 32; ++kk) {
            float4 a  = *(const float4*)&As[kk][ty * 4];
            float4 b0 = *(const float4*)&Bs[kk][tx * 4];
            float4 b1 = *(const float4*)&Bs[kk][64 + tx * 4];
            float av[4] = {a.x, a.y, a.z, a.w};
            float bv[8] = {b0.x, b0.y, b0.z, b0.w, b1.x, b1.y, b1.z, b1.w};
#pragma unroll
            for (int i = 0; i < 4; ++i)
#pragma unroll
                for (int j = 0; j < 8; ++j)
                    acc[i][j] = fmaf(av[i], bv[j], acc[i][j]);
        }
        __syncthreads();
    }
#pragma unroll
    for (int i = 0; i < 4; ++i) {
        int row = n0 + ty * 4 + i;
        if (row < n) {
            float* po = out + (size_t)row * DIM;
#pragma unroll
            for (int j = 0; j < 4; ++j) {
                po[tx*4 + j]      = acc[i][j]     + bias[tx*4 + j];
                po[64 + tx*4 + j] = acc[i][j + 4] + bias[64 + tx*4 + j];
            }
        }
    }
}

// ---------------- per-node attention coefficients ----------------
__global__ __launch_bounds__(256) void alpha_nodes(
    const float* __restrict__ xl, const float* __restrict__ attl,
    const float* __restrict__ attr, float* __restrict__ al,
    float* __restrict__ ar, int n)
{
    int node = blockIdx.x * 4 + (threadIdx.x >> 6);
    if (node >= n) return;
    int lane = threadIdx.x & 63;
    float v0 = xl[(size_t)node * DIM + lane];
    float v1 = xl[(size_t)node * DIM + 64 + lane];
    float l0 = v0 * attl[lane],      r0 = v0 * attr[lane];
    float l1 = v1 * attl[64 + lane], r1 = v1 * attr[64 + lane];
#pragma unroll
    for (int off = 16; off >= 1; off >>= 1) {
        l0 += __shfl_xor(l0, off); r0 += __shfl_xor(r0, off);
        l1 += __shfl_xor(l1, off); r1 += __shfl_xor(r1, off);
    }
    if ((lane & 31) == 0) {
        int h = lane >> 5;
        al[node*4 + h]     = l0; ar[node*4 + h]     = r0;
        al[node*4 + 2 + h] = l1; ar[node*4 + 2 + h] = r1;
    }
}

// ---------------- CSR build ----------------
__global__ __launch_bounds__(256) void deg_count(
    const int* __restrict__ dst, int* __restrict__ deg, int E)
{
    int e = blockIdx.x * blockDim.x + threadIdx.x;
    if (e < E) atomicAdd(&deg[dst[e]], 1);
}

__global__ __launch_bounds__(256) void scan_blocks(
    const int* __restrict__ deg, int* __restrict__ rowptr,
    int* __restrict__ partials, int n)
{
    __shared__ int tot[256];
    int t = threadIdx.x;
    int base = blockIdx.x * 1024 + t * 4;
    int v[4];
#pragma unroll
    for (int j = 0; j < 4; ++j) v[j] = (base + j < n) ? deg[base + j] : 0;
    int p1 = v[0], p2 = p1 + v[1], p3 = p2 + v[2], sum4 = p3 + v[3];
    tot[t] = sum4;
    __syncthreads();
    int val = sum4;
    for (int off = 1; off < 256; off <<= 1) {
        int other = (t >= off) ? tot[t - off] : 0;
        __syncthreads();
        val += other;
        tot[t] = val;
        __syncthreads();
    }
    int excl = val - sum4;
    if (base < n)     rowptr[base]     = excl;
    if (base+1 < n)   rowptr[base+1]   = excl + p1;
    if (base+2 < n)   rowptr[base+2]   = excl + p2;
    if (base+3 < n)   rowptr[base+3]   = excl + p3;
    if (t == 255) partials[blockIdx.x] = val;
}

__global__ __launch_bounds__(256) void scan_partials(
    int* __restrict__ partials, int nb, int* __restrict__ rowptr, int n)
{
    __shared__ int tot[256];
    int t = threadIdx.x;
    int v = (t < nb) ? partials[t] : 0;
    tot[t] = v;
    __syncthreads();
    int val = v;
    for (int off = 1; off < 256; off <<= 1) {
        int other = (t >= off) ? tot[t - off] : 0;
        __syncthreads();
        val += other;
        tot[t] = val;
        __syncthreads();
    }
    if (t < nb) partials[t] = val - v;
    if (t == 255) rowptr[n] = val;
}

__global__ __launch_bounds__(256) void add_offsets(
    int* __restrict__ rowptr, int* __restrict__ wpos,
    const int* __restrict__ partials, int n)
{
    int base = blockIdx.x * 1024 + threadIdx.x * 4;
    int off = partials[blockIdx.x];
#pragma unroll
    for (int j = 0; j < 4; ++j) {
        int i = base + j;
        if (i < n) { int r = rowptr[i] + off; rowptr[i] = r; wpos[i] = r; }
    }
}

__global__ __launch_bounds__(256) void scatter_edges(
    const int* __restrict__ src, const int* __restrict__ dst,
    int* __restrict__ wpos, int* __restrict__ col, int E)
{
    int e = blockIdx.x * blockDim.x + threadIdx.x;
    if (e >= E) return;
    int p = atomicAdd(&wpos[dst[e]], 1);
    col[p] = src[e];
}

// ---- serial accumulate over one chunk of <=64 edges; weights in LDS ----
__device__ __forceinline__ void agg_chunk(
    const int* __restrict__ col, int base, int cn,
    const float* __restrict__ wl,            // LDS ptr, lane's head comp, stride 4 floats
    const float* __restrict__ xlrow,         // xl + lane*2
    float& A0, float& A1, float& B0, float& B1)
{
    int i = 0;
    for (; i + 4 <= cn; i += 4) {
        int s0 = col[base+i], s1 = col[base+i+1], s2 = col[base+i+2], s3 = col[base+i+3];
        float w0 = wl[(i+0)*4], w1 = wl[(i+1)*4], w2 = wl[(i+2)*4], w3 = wl[(i+3)*4];
        float2 v0 = *(const float2*)(xlrow + (size_t)s0 * DIM);
        float2 v1 = *(const float2*)(xlrow + (size_t)s1 * DIM);
        float2 v2 = *(const float2*)(xlrow + (size_t)s2 * DIM);
        float2 v3 = *(const float2*)(xlrow + (size_t)s3 * DIM);
        A0 = fmaf(w0, v0.x, A0); A1 = fmaf(w0, v0.y, A1);
        B0 = fmaf(w1, v1.x, B0); B1 = fmaf(w1, v1.y, B1);
        A0 = fmaf(w2, v2.x, A0); A1 = fmaf(w2, v2.y, A1);
        B0 = fmaf(w3, v3.x, B0); B1 = fmaf(w3, v3.y, B1);
    }
    for (; i < cn; ++i) {
        int s = col[base+i];
        float w = wl[i*4];
        float2 v = *(const float2*)(xlrow + (size_t)s * DIM);
        A0 = fmaf(w, v.x, A0); A1 = fmaf(w, v.y, A1);
    }
}

// ---------------- fused per-node softmax + aggregate (gather, no atomics) -----
// one wave per dst node; per-edge weight computed ONCE (one lane per edge),
// staged in LDS; phase C: unroll-4 {LDS w bcast, xl float2 gather, 2 fmaf}.
__global__ __launch_bounds__(256) void gat_aggregate(
    const int* __restrict__ rowptr, const int* __restrict__ col,
    const float* __restrict__ al, const float* __restrict__ ar,
    const float* __restrict__ xl, float* __restrict__ out, int n)
{
    __shared__ float4 wlds[4][64];
    int wid = threadIdx.x >> 6;
    int node = blockIdx.x * 4 + wid;
    if (node >= n) return;
    int lane = threadIdx.x & 63;
    int r0 = rowptr[node], r1 = rowptr[node + 1];
    int deg = r1 - r0;
    float* po = out + (size_t)node * DIM + lane * 2;
    if (deg == 0) { *(float2*)po = make_float2(0.f, 0.f); return; }

    float4 arv = *(const float4*)(ar + (size_t)node * 4);
    int h = lane >> 4;
    const float* wl = (const float*)&wlds[wid][0] + h;
    const float* xlrow = xl + lane * 2;
    float A0 = 0.f, A1 = 0.f, B0 = 0.f, B1 = 0.f;
    float4 inv4;

    if (deg <= 64) {
        // --- single-chunk fast path: one gather, one exp per edge ---
        float4 l4 = make_float4(-1e30f, -1e30f, -1e30f, -1e30f);
        if (lane < deg) {
            int s = col[r0 + lane];
            float4 a = *(const float4*)(al + (size_t)s * 4);
            l4 = lrelu4(arv, a);
        }
        float4 m4 = redmax4(l4);
        float4 p4 = make_float4(0.f, 0.f, 0.f, 0.f);
        if (lane < deg) {
            p4.x = __expf(l4.x - m4.x); p4.y = __expf(l4.y - m4.y);
            p4.z = __expf(l4.z - m4.z); p4.w = __expf(l4.w - m4.w);
        }
        float4 s4 = redsum4(p4);
        inv4 = make_float4(1.f/(s4.x+1e-16f), 1.f/(s4.y+1e-16f),
                           1.f/(s4.z+1e-16f), 1.f/(s4.w+1e-16f));
        if (lane < deg) wlds[wid][lane] = p4;
        __asm__ volatile("s_waitcnt lgkmcnt(0)" ::: "memory");
        __builtin_amdgcn_sched_barrier(0);
        agg_chunk(col, r0, deg, wl, xlrow, A0, A1, B0, B1);
    } else {
        // --- generic chunked path (rare) ---
        float4 m4 = make_float4(-1e30f, -1e30f, -1e30f, -1e30f);
        for (int i = lane; i < deg; i += 64) {
            int s = col[r0 + i];
            float4 a = *(const float4*)(al + (size_t)s * 4);
            float4 t = lrelu4(arv, a);
            m4.x = fmaxf(m4.x, t.x); m4.y = fmaxf(m4.y, t.y);
            m4.z = fmaxf(m4.z, t.z); m4.w = fmaxf(m4.w, t.w);
        }
        m4 = redmax4(m4);
        float4 s4 = make_float4(0.f, 0.f, 0.f, 0.f);
        for (int i = lane; i < deg; i += 64) {
            int s = col[r0 + i];
            float4 a = *(const float4*)(al + (size_t)s * 4);
            float4 t = lrelu4(arv, a);
            s4.x += __expf(t.x - m4.x); s4.y += __expf(t.y - m4.y);
            s4.z += __expf(t.z - m4.z); s4.w += __expf(t.w - m4.w);
        }
        s4 = redsum4(s4);
        inv4 = make_float4(1.f/(s4.x+1e-16f), 1.f/(s4.y+1e-16f),
                           1.f/(s4.z+1e-16f), 1.f/(s4.w+1e-16f));
        for (int c0 = 0; c0 < deg; c0 += 64) {
            int cn = min(64, deg - c0);
            if (lane < cn) {
                int s = col[r0 + c0 + lane];
                float4 a = *(const float4*)(al + (size_t)s * 4);
                float4 t = lrelu4(arv, a);
                float4 p;
                p.x = __expf(t.x - m4.x); p.y = __expf(t.y - m4.y);
                p.z = __expf(t.z - m4.z); p.w = __expf(t.w - m4.w);
                wlds[wid][lane] = p;
            }
            __asm__ volatile("s_waitcnt lgkmcnt(0)" ::: "memory");
            __builtin_amdgcn_sched_barrier(0);
            agg_chunk(col, r0 + c0, cn, wl, xlrow, A0, A1, B0, B1);
        }
    }
    float invh = (h == 0) ? inv4.x : (h == 1) ? inv4.y : (h == 2) ? inv4.z : inv4.w;
    *(float2*)po = make_float2((A0 + B0) * invh, (A1 + B1) * invh);
}

// ---------------- graph pooling: segmented (batch is sorted) ----------------
__global__ __launch_bounds__(256) void pool_nodes_seg(
    const float* __restrict__ h, const int* __restrict__ batch,
    float* __restrict__ pooled, int n)
{
    int wid = threadIdx.x >> 6;
    int lane = threadIdx.x & 63;
    int start = blockIdx.x * POOL_CHUNK;
    int end = min(start + POOL_CHUNK, n);
    float a0 = 0.f, a1 = 0.f;
    int curg = -1;
    for (int node = start + wid; node < end; node += 4) {
        int g = batch[node];
        if (g != curg) {
            if (curg >= 0) {
                unsafeAtomicAdd(pooled + (size_t)curg * DIM + lane*2,     a0);
                unsafeAtomicAdd(pooled + (size_t)curg * DIM + lane*2 + 1, a1);
            }
            curg = g; a0 = 0.f; a1 = 0.f;
        }
        float2 v = *(const float2*)(h + (size_t)node * DIM + lane * 2);
        a0 += fmaxf(v.x, 0.f);
        a1 += fmaxf(v.y, 0.f);
    }
    if (curg >= 0) {
        unsafeAtomicAdd(pooled + (size_t)curg * DIM + lane*2,     a0);
        unsafeAtomicAdd(pooled + (size_t)curg * DIM + lane*2 + 1, a1);
    }
}

// ---------------- final projection ----------------
__global__ __launch_bounds__(256) void proj_out(
    const float* __restrict__ pooled, const float* __restrict__ W,
    const float* __restrict__ b, float* __restrict__ out, int G)
{
    int idx = blockIdx.x * blockDim.x + threadIdx.x;
    if (idx >= G * 32) return;
    int g = idx >> 5, j = idx & 31;
    const float* pr = pooled + (size_t)g * DIM;
    const float* wr = W + (size_t)j * DIM;
    float acc = 0.f;
#pragma unroll
    for (int k = 0; k < DIM; ++k) acc = fmaf(pr[k], wr[k], acc);
    out[idx] = acc + b[j];
}

extern "C" void kernel_launch(void* const* d_in, const int* in_sizes, int n_in,
                              void* d_out, int out_size, void* d_ws, size_t ws_size,
                              hipStream_t stream)
{
    const float* x      = (const float*)d_in[0];
    const int*   eidx   = (const int*)d_in[1];
    const int*   batch  = (const int*)d_in[2];
    const float* Ws     = (const float*)d_in[3];
    const float* bs     = (const float*)d_in[4];
    const float* attls  = (const float*)d_in[5];
    const float* attrs  = (const float*)d_in[6];
    const float* projW  = (const float*)d_in[7];
    const float* projb  = (const float*)d_in[8];

    const int N = in_sizes[0] / DIM;
    const int E = in_sizes[1] / 2;
    const int G = out_size / 32;
    const int* src = eidx;
    const int* dst = eidx + E;

    char* ws = (char*)d_ws;
    size_t o = 0;
    auto alloc = [&](size_t bytes) { char* p = ws + o; o += (bytes + 255) & ~255ull; return p; };
    float* hA     = (float*)alloc((size_t)N * DIM * 4);
    float* hB     = (float*)alloc((size_t)N * DIM * 4);
    float* xl     = (float*)alloc((size_t)N * DIM * 4);
    float* al     = (float*)alloc((size_t)N * 4 * 4);
    float* ar     = (float*)alloc((size_t)N * 4 * 4);
    int*   rowptr = (int*)alloc((size_t)(N + 1) * 4);
    int*   wpos   = (int*)alloc((size_t)N * 4);
    int*   deg    = (int*)alloc((size_t)N * 4);
    int*   colv   = (int*)alloc((size_t)E * 4);
    int*   parts  = (int*)alloc(256 * 4);
    float* pooled = (float*)alloc((size_t)G * DIM * 4);

    // ---- CSR build (once; edge structure shared by all 3 layers) ----
    const int nb = (N + 1023) / 1024;
    hipMemsetAsync(deg, 0, (size_t)N * 4, stream);
    deg_count<<<(E + 255) / 256, 256, 0, stream>>>(dst, deg, E);
    scan_blocks<<<nb, 256, 0, stream>>>(deg, rowptr, parts, N);
    scan_partials<<<1, 256, 0, stream>>>(parts, nb, rowptr, N);
    add_offsets<<<nb, 256, 0, stream>>>(rowptr, wpos, parts, N);
    scatter_edges<<<(E + 255) / 256, 256, 0, stream>>>(src, dst, wpos, colv, E);

    // ---- 3 GAT layers ----
    const float* hin = x;
    float* houts[3] = {hA, hB, hA};
    for (int l = 0; l < 3; ++l) {
        float* hout = houts[l];
        dim3 gb((N + 63) / 64);
        if (l == 0) gemm_nodes<false><<<gb, 256, 0, stream>>>(hin, Ws + (size_t)l*DIM*DIM, bs + l*DIM, xl, N);
        else        gemm_nodes<true ><<<gb, 256, 0, stream>>>(hin, Ws + (size_t)l*DIM*DIM, bs + l*DIM, xl, N);
        alpha_nodes<<<(N + 3) / 4, 256, 0, stream>>>(xl, attls + l*DIM, attrs + l*DIM, al, ar, N);
        gat_aggregate<<<(N + 3) / 4, 256, 0, stream>>>(rowptr, colv, al, ar, xl, hout, N);
        hin = hout;
    }

    // ---- pool + projection ----
    hipMemsetAsync(pooled, 0, (size_t)G * DIM * 4, stream);
    pool_nodes_seg<<<(N + POOL_CHUNK - 1) / POOL_CHUNK, 256, 0, stream>>>(hA, batch, pooled, N);
    proj_out<<<(G * 32 + 255) / 256, 256, 0, stream>>>(pooled, projW, projb, (float*)d_out, G);
}

// Round 5
// 380.403 us; speedup vs baseline: 8.2282x; 1.1845x over previous
//
#include <hip/hip_runtime.h>
#include <hip/hip_bf16.h>

#define NHEADS 4
#define DIM 128
#define NEG_SLOPE 0.2f
#define POOL_CHUNK 256

typedef __bf16 bf16x8 __attribute__((ext_vector_type(8)));
typedef float  f32x4  __attribute__((ext_vector_type(4)));

__device__ __forceinline__ float lrelu(float x) { return x > 0.f ? x : NEG_SLOPE * x; }
__device__ __forceinline__ float4 lrelu4(float4 a, float4 b) {
    return make_float4(lrelu(a.x + b.x), lrelu(a.y + b.y), lrelu(a.z + b.z), lrelu(a.w + b.w));
}
__device__ __forceinline__ float4 redmax4(float4 v) {
#pragma unroll
    for (int off = 32; off >= 1; off >>= 1) {
        v.x = fmaxf(v.x, __shfl_xor(v.x, off));
        v.y = fmaxf(v.y, __shfl_xor(v.y, off));
        v.z = fmaxf(v.z, __shfl_xor(v.z, off));
        v.w = fmaxf(v.w, __shfl_xor(v.w, off));
    }
    return v;
}
__device__ __forceinline__ float4 redsum4(float4 v) {
#pragma unroll
    for (int off = 32; off >= 1; off >>= 1) {
        v.x += __shfl_xor(v.x, off);
        v.y += __shfl_xor(v.y, off);
        v.z += __shfl_xor(v.z, off);
        v.w += __shfl_xor(v.w, off);
    }
    return v;
}

// ---------------- W pre-pack: fp32 [3][128][128] -> bf16 MFMA B-fragments ----------
// Fragment-major layout: elem index = ((layer*32 + g*4 + kk)*64 + lane)*8 + j
// holds W[layer][col=g*16+(lane&15)][k=kk*32+(lane>>4)*8+j] as bf16.
__global__ __launch_bounds__(256) void pack_w(
    const float* __restrict__ Ws, __bf16* __restrict__ Wb, int total)
{
    int o = blockIdx.x * 256 + threadIdx.x;
    if (o >= total) return;
    int layer = o >> 14;
    int t = o & 16383;
    int j = t & 7, l = (t >> 3) & 63, kk = (t >> 9) & 3, g = t >> 11;
    int col = g * 16 + (l & 15);
    int k = kk * 32 + (l >> 4) * 8 + j;
    Wb[o] = (__bf16)Ws[(size_t)layer * 16384 + col * 128 + k];
}

// ---------------- bf16-MFMA GEMM + fused attention coefficients ----------------
// block = 64 rows x 128 cols, 4 waves (16 rows each). K=128 in 4 steps of 32.
// A: fp32 global->reg->bf16 (optional relu). B: packed bf16 frags (coalesced).
// Epilogue: +bias, store xl fp32, and compute al/ar = xl . att_{l,r} per head
// via in-register partials + 16-lane xor-shuffle reduce.
template<bool RELU_IN>
__global__ __launch_bounds__(256) void gemm_mfma(
    const float* __restrict__ in, const uint4* __restrict__ Wb4,
    const float* __restrict__ bias,
    const float* __restrict__ attl, const float* __restrict__ attr,
    float* __restrict__ out, float* __restrict__ al, float* __restrict__ ar, int n)
{
    const int tid = threadIdx.x;
    const int wid = tid >> 6, l = tid & 63;
    const int rowA = blockIdx.x * 64 + wid * 16 + (l & 15);  // row this lane loads
    const int kchunk = (l >> 4) * 8;

    f32x4 acc[8];
#pragma unroll
    for (int g = 0; g < 8; ++g)
#pragma unroll
        for (int r = 0; r < 4; ++r) acc[g][r] = 0.f;

#pragma unroll
    for (int kk = 0; kk < 4; ++kk) {
        float av[8];
        if (rowA < n) {
            const float* p = in + (size_t)rowA * DIM + kk * 32 + kchunk;
            float4 x0 = *(const float4*)p;
            float4 x1 = *(const float4*)(p + 4);
            av[0]=x0.x; av[1]=x0.y; av[2]=x0.z; av[3]=x0.w;
            av[4]=x1.x; av[5]=x1.y; av[6]=x1.z; av[7]=x1.w;
            if (RELU_IN) {
#pragma unroll
                for (int i = 0; i < 8; ++i) av[i] = fmaxf(av[i], 0.f);
            }
        } else {
#pragma unroll
            for (int i = 0; i < 8; ++i) av[i] = 0.f;
        }
        bf16x8 afrag;
#pragma unroll
        for (int i = 0; i < 8; ++i) afrag[i] = (__bf16)av[i];
#pragma unroll
        for (int g = 0; g < 8; ++g) {
            uint4 u = Wb4[(g * 4 + kk) * 64 + l];
            bf16x8 bfrag = __builtin_bit_cast(bf16x8, u);
            acc[g] = __builtin_amdgcn_mfma_f32_16x16x32_bf16(afrag, bfrag, acc[g], 0, 0, 0);
        }
    }

    // ---- epilogue: bias + store + fused alpha partials ----
    const int rowbase = blockIdx.x * 64 + wid * 16 + (l >> 4) * 4;
    float pl[4][4], pr2[4][4];
#pragma unroll
    for (int r = 0; r < 4; ++r)
#pragma unroll
        for (int h = 0; h < 4; ++h) { pl[r][h] = 0.f; pr2[r][h] = 0.f; }

#pragma unroll
    for (int g = 0; g < 8; ++g) {
        int col = g * 16 + (l & 15);
        float bg = bias[col], alg = attl[col], arg = attr[col];
        int h = g >> 1;
#pragma unroll
        for (int r = 0; r < 4; ++r) {
            float v = acc[g][r] + bg;
            int row = rowbase + r;
            if (row < n) out[(size_t)row * DIM + col] = v;
            pl[r][h]  = fmaf(v, alg, pl[r][h]);
            pr2[r][h] = fmaf(v, arg, pr2[r][h]);
        }
    }
#pragma unroll
    for (int off = 1; off <= 8; off <<= 1) {
#pragma unroll
        for (int r = 0; r < 4; ++r)
#pragma unroll
            for (int h = 0; h < 4; ++h) {
                pl[r][h]  += __shfl_xor(pl[r][h], off);
                pr2[r][h] += __shfl_xor(pr2[r][h], off);
            }
    }
    if ((l & 15) == 0) {
#pragma unroll
        for (int r = 0; r < 4; ++r) {
            int row = rowbase + r;
            if (row < n) {
#pragma unroll
                for (int h = 0; h < 4; ++h) {
                    al[row * 4 + h] = pl[r][h];
                    ar[row * 4 + h] = pr2[r][h];
                }
            }
        }
    }
}

// ---------------- CSR build ----------------
__global__ __launch_bounds__(256) void deg_count(
    const int* __restrict__ dst, int* __restrict__ deg, int E)
{
    int e = blockIdx.x * blockDim.x + threadIdx.x;
    if (e < E) atomicAdd(&deg[dst[e]], 1);
}

__global__ __launch_bounds__(256) void scan_blocks(
    const int* __restrict__ deg, int* __restrict__ rowptr,
    int* __restrict__ partials, int n)
{
    __shared__ int tot[256];
    int t = threadIdx.x;
    int base = blockIdx.x * 1024 + t * 4;
    int v[4];
#pragma unroll
    for (int j = 0; j < 4; ++j) v[j] = (base + j < n) ? deg[base + j] : 0;
    int p1 = v[0], p2 = p1 + v[1], p3 = p2 + v[2], sum4 = p3 + v[3];
    tot[t] = sum4;
    __syncthreads();
    int val = sum4;
    for (int off = 1; off < 256; off <<= 1) {
        int other = (t >= off) ? tot[t - off] : 0;
        __syncthreads();
        val += other;
        tot[t] = val;
        __syncthreads();
    }
    int excl = val - sum4;
    if (base < n)     rowptr[base]     = excl;
    if (base+1 < n)   rowptr[base+1]   = excl + p1;
    if (base+2 < n)   rowptr[base+2]   = excl + p2;
    if (base+3 < n)   rowptr[base+3]   = excl + p3;
    if (t == 255) partials[blockIdx.x] = val;
}

__global__ __launch_bounds__(256) void scan_partials(
    int* __restrict__ partials, int nb, int* __restrict__ rowptr, int n)
{
    __shared__ int tot[256];
    int t = threadIdx.x;
    int v = (t < nb) ? partials[t] : 0;
    tot[t] = v;
    __syncthreads();
    int val = v;
    for (int off = 1; off < 256; off <<= 1) {
        int other = (t >= off) ? tot[t - off] : 0;
        __syncthreads();
        val += other;
        tot[t] = val;
        __syncthreads();
    }
    if (t < nb) partials[t] = val - v;
    if (t == 255) rowptr[n] = val;
}

__global__ __launch_bounds__(256) void add_offsets(
    int* __restrict__ rowptr, int* __restrict__ wpos,
    const int* __restrict__ partials, int n)
{
    int base = blockIdx.x * 1024 + threadIdx.x * 4;
    int off = partials[blockIdx.x];
#pragma unroll
    for (int j = 0; j < 4; ++j) {
        int i = base + j;
        if (i < n) { int r = rowptr[i] + off; rowptr[i] = r; wpos[i] = r; }
    }
}

__global__ __launch_bounds__(256) void scatter_edges(
    const int* __restrict__ src, const int* __restrict__ dst,
    int* __restrict__ wpos, int* __restrict__ col, int E)
{
    int e = blockIdx.x * blockDim.x + threadIdx.x;
    if (e >= E) return;
    int p = atomicAdd(&wpos[dst[e]], 1);
    col[p] = src[e];
}

// ---- serial accumulate over one chunk of <=64 edges; weights in LDS ----
__device__ __forceinline__ void agg_chunk(
    const int* __restrict__ col, int base, int cn,
    const float* __restrict__ wl,
    const float* __restrict__ xlrow,
    float& A0, float& A1, float& B0, float& B1)
{
    int i = 0;
    for (; i + 4 <= cn; i += 4) {
        int s0 = col[base+i], s1 = col[base+i+1], s2 = col[base+i+2], s3 = col[base+i+3];
        float w0 = wl[(i+0)*4], w1 = wl[(i+1)*4], w2 = wl[(i+2)*4], w3 = wl[(i+3)*4];
        float2 v0 = *(const float2*)(xlrow + (size_t)s0 * DIM);
        float2 v1 = *(const float2*)(xlrow + (size_t)s1 * DIM);
        float2 v2 = *(const float2*)(xlrow + (size_t)s2 * DIM);
        float2 v3 = *(const float2*)(xlrow + (size_t)s3 * DIM);
        A0 = fmaf(w0, v0.x, A0); A1 = fmaf(w0, v0.y, A1);
        B0 = fmaf(w1, v1.x, B0); B1 = fmaf(w1, v1.y, B1);
        A0 = fmaf(w2, v2.x, A0); A1 = fmaf(w2, v2.y, A1);
        B0 = fmaf(w3, v3.x, B0); B1 = fmaf(w3, v3.y, B1);
    }
    for (; i < cn; ++i) {
        int s = col[base+i];
        float w = wl[i*4];
        float2 v = *(const float2*)(xlrow + (size_t)s * DIM);
        A0 = fmaf(w, v.x, A0); A1 = fmaf(w, v.y, A1);
    }
}

// ---------------- fused per-node softmax + aggregate (gather, no atomics) -----
__global__ __launch_bounds__(256) void gat_aggregate(
    const int* __restrict__ rowptr, const int* __restrict__ col,
    const float* __restrict__ al, const float* __restrict__ ar,
    const float* __restrict__ xl, float* __restrict__ out, int n)
{
    __shared__ float4 wlds[4][64];
    int wid = threadIdx.x >> 6;
    int node = blockIdx.x * 4 + wid;
    if (node >= n) return;
    int lane = threadIdx.x & 63;
    int r0 = rowptr[node], r1 = rowptr[node + 1];
    int deg = r1 - r0;
    float* po = out + (size_t)node * DIM + lane * 2;
    if (deg == 0) { *(float2*)po = make_float2(0.f, 0.f); return; }

    float4 arv = *(const float4*)(ar + (size_t)node * 4);
    int h = lane >> 4;
    const float* wl = (const float*)&wlds[wid][0] + h;
    const float* xlrow = xl + lane * 2;
    float A0 = 0.f, A1 = 0.f, B0 = 0.f, B1 = 0.f;
    float4 inv4;

    if (deg <= 64) {
        float4 l4 = make_float4(-1e30f, -1e30f, -1e30f, -1e30f);
        if (lane < deg) {
            int s = col[r0 + lane];
            float4 a = *(const float4*)(al + (size_t)s * 4);
            l4 = lrelu4(arv, a);
        }
        float4 m4 = redmax4(l4);
        float4 p4 = make_float4(0.f, 0.f, 0.f, 0.f);
        if (lane < deg) {
            p4.x = __expf(l4.x - m4.x); p4.y = __expf(l4.y - m4.y);
            p4.z = __expf(l4.z - m4.z); p4.w = __expf(l4.w - m4.w);
        }
        float4 s4 = redsum4(p4);
        inv4 = make_float4(1.f/(s4.x+1e-16f), 1.f/(s4.y+1e-16f),
                           1.f/(s4.z+1e-16f), 1.f/(s4.w+1e-16f));
        if (lane < deg) wlds[wid][lane] = p4;
        __asm__ volatile("s_waitcnt lgkmcnt(0)" ::: "memory");
        __builtin_amdgcn_sched_barrier(0);
        agg_chunk(col, r0, deg, wl, xlrow, A0, A1, B0, B1);
    } else {
        float4 m4 = make_float4(-1e30f, -1e30f, -1e30f, -1e30f);
        for (int i = lane; i < deg; i += 64) {
            int s = col[r0 + i];
            float4 a = *(const float4*)(al + (size_t)s * 4);
            float4 t = lrelu4(arv, a);
            m4.x = fmaxf(m4.x, t.x); m4.y = fmaxf(m4.y, t.y);
            m4.z = fmaxf(m4.z, t.z); m4.w = fmaxf(m4.w, t.w);
        }
        m4 = redmax4(m4);
        float4 s4 = make_float4(0.f, 0.f, 0.f, 0.f);
        for (int i = lane; i < deg; i += 64) {
            int s = col[r0 + i];
            float4 a = *(const float4*)(al + (size_t)s * 4);
            float4 t = lrelu4(arv, a);
            s4.x += __expf(t.x - m4.x); s4.y += __expf(t.y - m4.y);
            s4.z += __expf(t.z - m4.z); s4.w += __expf(t.w - m4.w);
        }
        s4 = redsum4(s4);
        inv4 = make_float4(1.f/(s4.x+1e-16f), 1.f/(s4.y+1e-16f),
                           1.f/(s4.z+1e-16f), 1.f/(s4.w+1e-16f));
        for (int c0 = 0; c0 < deg; c0 += 64) {
            int cn = min(64, deg - c0);
            if (lane < cn) {
                int s = col[r0 + c0 + lane];
                float4 a = *(const float4*)(al + (size_t)s * 4);
                float4 t = lrelu4(arv, a);
                float4 p;
                p.x = __expf(t.x - m4.x); p.y = __expf(t.y - m4.y);
                p.z = __expf(t.z - m4.z); p.w = __expf(t.w - m4.w);
                wlds[wid][lane] = p;
            }
            __asm__ volatile("s_waitcnt lgkmcnt(0)" ::: "memory");
            __builtin_amdgcn_sched_barrier(0);
            agg_chunk(col, r0 + c0, cn, wl, xlrow, A0, A1, B0, B1);
        }
    }
    float invh = (h == 0) ? inv4.x : (h == 1) ? inv4.y : (h == 2) ? inv4.z : inv4.w;
    *(float2*)po = make_float2((A0 + B0) * invh, (A1 + B1) * invh);
}

// ---------------- graph pooling: segmented (batch is sorted) ----------------
__global__ __launch_bounds__(256) void pool_nodes_seg(
    const float* __restrict__ h, const int* __restrict__ batch,
    float* __restrict__ pooled, int n)
{
    int wid = threadIdx.x >> 6;
    int lane = threadIdx.x & 63;
    int start = blockIdx.x * POOL_CHUNK;
    int end = min(start + POOL_CHUNK, n);
    float a0 = 0.f, a1 = 0.f;
    int curg = -1;
    for (int node = start + wid; node < end; node += 4) {
        int g = batch[node];
        if (g != curg) {
            if (curg >= 0) {
                unsafeAtomicAdd(pooled + (size_t)curg * DIM + lane*2,     a0);
                unsafeAtomicAdd(pooled + (size_t)curg * DIM + lane*2 + 1, a1);
            }
            curg = g; a0 = 0.f; a1 = 0.f;
        }
        float2 v = *(const float2*)(h + (size_t)node * DIM + lane * 2);
        a0 += fmaxf(v.x, 0.f);
        a1 += fmaxf(v.y, 0.f);
    }
    if (curg >= 0) {
        unsafeAtomicAdd(pooled + (size_t)curg * DIM + lane*2,     a0);
        unsafeAtomicAdd(pooled + (size_t)curg * DIM + lane*2 + 1, a1);
    }
}

// ---------------- final projection ----------------
__global__ __launch_bounds__(256) void proj_out(
    const float* __restrict__ pooled, const float* __restrict__ W,
    const float* __restrict__ b, float* __restrict__ out, int G)
{
    int idx = blockIdx.x * blockDim.x + threadIdx.x;
    if (idx >= G * 32) return;
    int g = idx >> 5, j = idx & 31;
    const float* pr = pooled + (size_t)g * DIM;
    const float* wr = W + (size_t)j * DIM;
    float acc = 0.f;
#pragma unroll
    for (int k = 0; k < DIM; ++k) acc = fmaf(pr[k], wr[k], acc);
    out[idx] = acc + b[j];
}

extern "C" void kernel_launch(void* const* d_in, const int* in_sizes, int n_in,
                              void* d_out, int out_size, void* d_ws, size_t ws_size,
                              hipStream_t stream)
{
    const float* x      = (const float*)d_in[0];
    const int*   eidx   = (const int*)d_in[1];
    const int*   batch  = (const int*)d_in[2];
    const float* Ws     = (const float*)d_in[3];
    const float* bs     = (const float*)d_in[4];
    const float* attls  = (const float*)d_in[5];
    const float* attrs  = (const float*)d_in[6];
    const float* projW  = (const float*)d_in[7];
    const float* projb  = (const float*)d_in[8];

    const int N = in_sizes[0] / DIM;
    const int E = in_sizes[1] / 2;
    const int G = out_size / 32;
    const int* src = eidx;
    const int* dst = eidx + E;

    char* ws = (char*)d_ws;
    size_t o = 0;
    auto alloc = [&](size_t bytes) { char* p = ws + o; o += (bytes + 255) & ~255ull; return p; };
    float*  hA     = (float*)alloc((size_t)N * DIM * 4);
    float*  hB     = (float*)alloc((size_t)N * DIM * 4);
    float*  xl     = (float*)alloc((size_t)N * DIM * 4);
    float*  al     = (float*)alloc((size_t)N * 4 * 4);
    float*  ar     = (float*)alloc((size_t)N * 4 * 4);
    int*    rowptr = (int*)alloc((size_t)(N + 1) * 4);
    int*    wpos   = (int*)alloc((size_t)N * 4);
    int*    deg    = (int*)alloc((size_t)N * 4);
    int*    colv   = (int*)alloc((size_t)E * 4);
    int*    parts  = (int*)alloc(256 * 4);
    float*  pooled = (float*)alloc((size_t)G * DIM * 4);
    __bf16* Wb     = (__bf16*)alloc((size_t)3 * 16384 * 2);

    // ---- one-time prep: W fragment pack + CSR build ----
    const int wtot = 3 * 16384;
    pack_w<<<(wtot + 255) / 256, 256, 0, stream>>>(Ws, Wb, wtot);

    const int nb = (N + 1023) / 1024;
    hipMemsetAsync(deg, 0, (size_t)N * 4, stream);
    deg_count<<<(E + 255) / 256, 256, 0, stream>>>(dst, deg, E);
    scan_blocks<<<nb, 256, 0, stream>>>(deg, rowptr, parts, N);
    scan_partials<<<1, 256, 0, stream>>>(parts, nb, rowptr, N);
    add_offsets<<<nb, 256, 0, stream>>>(rowptr, wpos, parts, N);
    scatter_edges<<<(E + 255) / 256, 256, 0, stream>>>(src, dst, wpos, colv, E);

    // ---- 3 GAT layers ----
    const float* hin = x;
    float* houts[3] = {hA, hB, hA};
    for (int l = 0; l < 3; ++l) {
        float* hout = houts[l];
        dim3 gb((N + 63) / 64);
        const uint4* Wb4 = (const uint4*)(Wb + (size_t)l * 16384);
        if (l == 0)
            gemm_mfma<false><<<gb, 256, 0, stream>>>(hin, Wb4, bs + l*DIM,
                attls + l*DIM, attrs + l*DIM, xl, al, ar, N);
        else
            gemm_mfma<true ><<<gb, 256, 0, stream>>>(hin, Wb4, bs + l*DIM,
                attls + l*DIM, attrs + l*DIM, xl, al, ar, N);
        gat_aggregate<<<(N + 3) / 4, 256, 0, stream>>>(rowptr, colv, al, ar, xl, hout, N);
        hin = hout;
    }

    // ---- pool + projection ----
    hipMemsetAsync(pooled, 0, (size_t)G * DIM * 4, stream);
    pool_nodes_seg<<<(N + POOL_CHUNK - 1) / POOL_CHUNK, 256, 0, stream>>>(hA, batch, pooled, N);
    proj_out<<<(G * 32 + 255) / 256, 256, 0, stream>>>(pooled, projW, projb, (float*)d_out, G);
}

// Round 6
// 328.565 us; speedup vs baseline: 9.5264x; 1.1578x over previous
//
#include <hip/hip_runtime.h>
#include <hip/hip_bf16.h>

#define NHEADS 4
#define DIM 128
#define NEG_SLOPE 0.2f
#define POOL_CHUNK 256

typedef __bf16 bf16x8 __attribute__((ext_vector_type(8)));
typedef float  f32x4  __attribute__((ext_vector_type(4)));

__device__ __forceinline__ float lrelu(float x) { return x > 0.f ? x : NEG_SLOPE * x; }
__device__ __forceinline__ float bf2f(unsigned short u) {
    return __uint_as_float(((unsigned)u) << 16);
}
__device__ __forceinline__ float4 lrelu4(float4 a, float4 b) {
    return make_float4(lrelu(a.x + b.x), lrelu(a.y + b.y), lrelu(a.z + b.z), lrelu(a.w + b.w));
}
__device__ __forceinline__ float4 redmax4(float4 v) {
#pragma unroll
    for (int off = 32; off >= 1; off >>= 1) {
        v.x = fmaxf(v.x, __shfl_xor(v.x, off));
        v.y = fmaxf(v.y, __shfl_xor(v.y, off));
        v.z = fmaxf(v.z, __shfl_xor(v.z, off));
        v.w = fmaxf(v.w, __shfl_xor(v.w, off));
    }
    return v;
}
__device__ __forceinline__ float4 redsum4(float4 v) {
#pragma unroll
    for (int off = 32; off >= 1; off >>= 1) {
        v.x += __shfl_xor(v.x, off);
        v.y += __shfl_xor(v.y, off);
        v.z += __shfl_xor(v.z, off);
        v.w += __shfl_xor(v.w, off);
    }
    return v;
}

// ---------------- W pre-pack: fp32 [3][128][128] -> bf16 MFMA B-fragments ----------
__global__ __launch_bounds__(256) void pack_w(
    const float* __restrict__ Ws, __bf16* __restrict__ Wb, int total)
{
    int o = blockIdx.x * 256 + threadIdx.x;
    if (o >= total) return;
    int layer = o >> 14;
    int t = o & 16383;
    int j = t & 7, l = (t >> 3) & 63, kk = (t >> 9) & 3, g = t >> 11;
    int col = g * 16 + (l & 15);
    int k = kk * 32 + (l >> 4) * 8 + j;
    Wb[o] = (__bf16)Ws[(size_t)layer * 16384 + col * 128 + k];
}

// ---------------- bf16-MFMA GEMM + fused attention coefficients ----------------
// Writes xl ONLY as bf16 (xlb) + per-node al/ar. A: fp32->bf16 in-reg.
template<bool RELU_IN>
__global__ __launch_bounds__(256) void gemm_mfma(
    const float* __restrict__ in, const uint4* __restrict__ Wb4,
    const float* __restrict__ bias,
    const float* __restrict__ attl, const float* __restrict__ attr,
    __bf16* __restrict__ xlb, float* __restrict__ al, float* __restrict__ ar, int n)
{
    const int tid = threadIdx.x;
    const int wid = tid >> 6, l = tid & 63;
    const int rowA = blockIdx.x * 64 + wid * 16 + (l & 15);
    const int kchunk = (l >> 4) * 8;

    f32x4 acc[8];
#pragma unroll
    for (int g = 0; g < 8; ++g)
#pragma unroll
        for (int r = 0; r < 4; ++r) acc[g][r] = 0.f;

#pragma unroll
    for (int kk = 0; kk < 4; ++kk) {
        float av[8];
        if (rowA < n) {
            const float* p = in + (size_t)rowA * DIM + kk * 32 + kchunk;
            float4 x0 = *(const float4*)p;
            float4 x1 = *(const float4*)(p + 4);
            av[0]=x0.x; av[1]=x0.y; av[2]=x0.z; av[3]=x0.w;
            av[4]=x1.x; av[5]=x1.y; av[6]=x1.z; av[7]=x1.w;
            if (RELU_IN) {
#pragma unroll
                for (int i = 0; i < 8; ++i) av[i] = fmaxf(av[i], 0.f);
            }
        } else {
#pragma unroll
            for (int i = 0; i < 8; ++i) av[i] = 0.f;
        }
        bf16x8 afrag;
#pragma unroll
        for (int i = 0; i < 8; ++i) afrag[i] = (__bf16)av[i];
#pragma unroll
        for (int g = 0; g < 8; ++g) {
            uint4 u = Wb4[(g * 4 + kk) * 64 + l];
            bf16x8 bfrag = __builtin_bit_cast(bf16x8, u);
            acc[g] = __builtin_amdgcn_mfma_f32_16x16x32_bf16(afrag, bfrag, acc[g], 0, 0, 0);
        }
    }

    // ---- epilogue: bias + bf16 xl store + fused alpha partials ----
    const int rowbase = blockIdx.x * 64 + wid * 16 + (l >> 4) * 4;
    float pl[4][4], pr2[4][4];
#pragma unroll
    for (int r = 0; r < 4; ++r)
#pragma unroll
        for (int h = 0; h < 4; ++h) { pl[r][h] = 0.f; pr2[r][h] = 0.f; }

#pragma unroll
    for (int g = 0; g < 8; ++g) {
        int col = g * 16 + (l & 15);
        float bg = bias[col], alg = attl[col], arg = attr[col];
        int h = g >> 1;
#pragma unroll
        for (int r = 0; r < 4; ++r) {
            float v = acc[g][r] + bg;
            int row = rowbase + r;
            if (row < n) xlb[(size_t)row * DIM + col] = (__bf16)v;
            pl[r][h]  = fmaf(v, alg, pl[r][h]);
            pr2[r][h] = fmaf(v, arg, pr2[r][h]);
        }
    }
#pragma unroll
    for (int off = 1; off <= 8; off <<= 1) {
#pragma unroll
        for (int r = 0; r < 4; ++r)
#pragma unroll
            for (int h = 0; h < 4; ++h) {
                pl[r][h]  += __shfl_xor(pl[r][h], off);
                pr2[r][h] += __shfl_xor(pr2[r][h], off);
            }
    }
    if ((l & 15) == 0) {
#pragma unroll
        for (int r = 0; r < 4; ++r) {
            int row = rowbase + r;
            if (row < n) {
#pragma unroll
                for (int h = 0; h < 4; ++h) {
                    al[row * 4 + h] = pl[r][h];
                    ar[row * 4 + h] = pr2[r][h];
                }
            }
        }
    }
}

// ---------------- CSR build ----------------
__global__ __launch_bounds__(256) void deg_count(
    const int* __restrict__ dst, int* __restrict__ deg, int E)
{
    int e = blockIdx.x * blockDim.x + threadIdx.x;
    if (e < E) atomicAdd(&deg[dst[e]], 1);
}

__global__ __launch_bounds__(256) void scan_blocks(
    const int* __restrict__ deg, int* __restrict__ rowptr,
    int* __restrict__ partials, int n)
{
    __shared__ int tot[256];
    int t = threadIdx.x;
    int base = blockIdx.x * 1024 + t * 4;
    int v[4];
#pragma unroll
    for (int j = 0; j < 4; ++j) v[j] = (base + j < n) ? deg[base + j] : 0;
    int p1 = v[0], p2 = p1 + v[1], p3 = p2 + v[2], sum4 = p3 + v[3];
    tot[t] = sum4;
    __syncthreads();
    int val = sum4;
    for (int off = 1; off < 256; off <<= 1) {
        int other = (t >= off) ? tot[t - off] : 0;
        __syncthreads();
        val += other;
        tot[t] = val;
        __syncthreads();
    }
    int excl = val - sum4;
    if (base < n)     rowptr[base]     = excl;
    if (base+1 < n)   rowptr[base+1]   = excl + p1;
    if (base+2 < n)   rowptr[base+2]   = excl + p2;
    if (base+3 < n)   rowptr[base+3]   = excl + p3;
    if (t == 255) partials[blockIdx.x] = val;
}

__global__ __launch_bounds__(256) void scan_partials(
    int* __restrict__ partials, int nb, int* __restrict__ rowptr, int n)
{
    __shared__ int tot[256];
    int t = threadIdx.x;
    int v = (t < nb) ? partials[t] : 0;
    tot[t] = v;
    __syncthreads();
    int val = v;
    for (int off = 1; off < 256; off <<= 1) {
        int other = (t >= off) ? tot[t - off] : 0;
        __syncthreads();
        val += other;
        tot[t] = val;
        __syncthreads();
    }
    if (t < nb) partials[t] = val - v;
    if (t == 255) rowptr[n] = val;
}

__global__ __launch_bounds__(256) void add_offsets(
    int* __restrict__ rowptr, int* __restrict__ wpos,
    const int* __restrict__ partials, int n)
{
    int base = blockIdx.x * 1024 + threadIdx.x * 4;
    int off = partials[blockIdx.x];
#pragma unroll
    for (int j = 0; j < 4; ++j) {
        int i = base + j;
        if (i < n) { int r = rowptr[i] + off; rowptr[i] = r; wpos[i] = r; }
    }
}

__global__ __launch_bounds__(256) void scatter_edges(
    const int* __restrict__ src, const int* __restrict__ dst,
    int* __restrict__ wpos, int* __restrict__ col, int E)
{
    int e = blockIdx.x * blockDim.x + threadIdx.x;
    if (e >= E) return;
    int p = atomicAdd(&wpos[dst[e]], 1);
    col[p] = src[e];
}

// ---- accumulate chunk of <=64 staged edges; 2 edges wide (32 lanes x 4ch) ----
// xp = xlb + c32*4; wl = &wlds[wid][0].x + h (stride 4 floats); q = lane>>5.
__device__ __forceinline__ void agg_chunk2(
    const int* __restrict__ slds, const float* __restrict__ wl,
    int cn, int q, const unsigned short* __restrict__ xp,
    f32x4& A, f32x4& B, f32x4& C, f32x4& D)
{
    int i = 0;
    for (; i + 8 <= cn; i += 8) {
        int e0 = i + q, e1 = i + 2 + q, e2 = i + 4 + q, e3 = i + 6 + q;
        int s0 = slds[e0], s1 = slds[e1], s2 = slds[e2], s3 = slds[e3];
        float w0 = wl[e0*4], w1 = wl[e1*4], w2 = wl[e2*4], w3 = wl[e3*4];
        ushort4 v0 = *(const ushort4*)(xp + (size_t)s0 * DIM);
        ushort4 v1 = *(const ushort4*)(xp + (size_t)s1 * DIM);
        ushort4 v2 = *(const ushort4*)(xp + (size_t)s2 * DIM);
        ushort4 v3 = *(const ushort4*)(xp + (size_t)s3 * DIM);
        A[0] = fmaf(w0, bf2f(v0.x), A[0]); A[1] = fmaf(w0, bf2f(v0.y), A[1]);
        A[2] = fmaf(w0, bf2f(v0.z), A[2]); A[3] = fmaf(w0, bf2f(v0.w), A[3]);
        B[0] = fmaf(w1, bf2f(v1.x), B[0]); B[1] = fmaf(w1, bf2f(v1.y), B[1]);
        B[2] = fmaf(w1, bf2f(v1.z), B[2]); B[3] = fmaf(w1, bf2f(v1.w), B[3]);
        C[0] = fmaf(w2, bf2f(v2.x), C[0]); C[1] = fmaf(w2, bf2f(v2.y), C[1]);
        C[2] = fmaf(w2, bf2f(v2.z), C[2]); C[3] = fmaf(w2, bf2f(v2.w), C[3]);
        D[0] = fmaf(w3, bf2f(v3.x), D[0]); D[1] = fmaf(w3, bf2f(v3.y), D[1]);
        D[2] = fmaf(w3, bf2f(v3.z), D[2]); D[3] = fmaf(w3, bf2f(v3.w), D[3]);
    }
    for (; i < cn; i += 2) {
        int e = i + q;
        if (e < cn) {
            int s = slds[e];
            float w = wl[e*4];
            ushort4 v = *(const ushort4*)(xp + (size_t)s * DIM);
            A[0] = fmaf(w, bf2f(v.x), A[0]); A[1] = fmaf(w, bf2f(v.y), A[1]);
            A[2] = fmaf(w, bf2f(v.z), A[2]); A[3] = fmaf(w, bf2f(v.w), A[3]);
        }
    }
}

// ---------------- fused per-node softmax + aggregate (bf16 gather) ----------
// one wave per dst node; lanes: q=lane>>5 (edge parity), c32=lane&31 owns ch 4*c32..+3.
__global__ __launch_bounds__(256) void gat_aggregate(
    const int* __restrict__ rowptr, const int* __restrict__ col,
    const float* __restrict__ al, const float* __restrict__ ar,
    const unsigned short* __restrict__ xlb, float* __restrict__ out, int n)
{
    __shared__ float4 wlds[4][64];
    __shared__ int    slds[4][64];
    int wid = threadIdx.x >> 6;
    int node = blockIdx.x * 4 + wid;
    if (node >= n) return;
    int lane = threadIdx.x & 63;
    int q = lane >> 5, c32 = lane & 31;
    int h = c32 >> 3;
    int r0 = rowptr[node], r1 = rowptr[node + 1];
    int deg = r1 - r0;
    if (deg == 0) {
        if (q == 0) *(float4*)(out + (size_t)node * DIM + c32 * 4) = make_float4(0.f,0.f,0.f,0.f);
        return;
    }

    float4 arv = *(const float4*)(ar + (size_t)node * 4);
    const float* wl = (const float*)&wlds[wid][0] + h;
    const unsigned short* xp = xlb + c32 * 4;
    f32x4 A = {0.f,0.f,0.f,0.f}, B = {0.f,0.f,0.f,0.f};
    f32x4 C = {0.f,0.f,0.f,0.f}, D = {0.f,0.f,0.f,0.f};
    float4 inv4;

    if (deg <= 64) {
        float4 l4 = make_float4(-1e30f, -1e30f, -1e30f, -1e30f);
        int s = 0;
        if (lane < deg) {
            s = col[r0 + lane];
            float4 a = *(const float4*)(al + (size_t)s * 4);
            l4 = lrelu4(arv, a);
        }
        float4 m4 = redmax4(l4);
        float4 p4 = make_float4(0.f, 0.f, 0.f, 0.f);
        if (lane < deg) {
            p4.x = __expf(l4.x - m4.x); p4.y = __expf(l4.y - m4.y);
            p4.z = __expf(l4.z - m4.z); p4.w = __expf(l4.w - m4.w);
        }
        float4 s4 = redsum4(p4);
        inv4 = make_float4(1.f/(s4.x+1e-16f), 1.f/(s4.y+1e-16f),
                           1.f/(s4.z+1e-16f), 1.f/(s4.w+1e-16f));
        if (lane < deg) { wlds[wid][lane] = p4; slds[wid][lane] = s; }
        __asm__ volatile("s_waitcnt lgkmcnt(0)" ::: "memory");
        __builtin_amdgcn_sched_barrier(0);
        agg_chunk2(&slds[wid][0], wl, deg, q, xp, A, B, C, D);
    } else {
        float4 m4 = make_float4(-1e30f, -1e30f, -1e30f, -1e30f);
        for (int i = lane; i < deg; i += 64) {
            int s = col[r0 + i];
            float4 a = *(const float4*)(al + (size_t)s * 4);
            float4 t = lrelu4(arv, a);
            m4.x = fmaxf(m4.x, t.x); m4.y = fmaxf(m4.y, t.y);
            m4.z = fmaxf(m4.z, t.z); m4.w = fmaxf(m4.w, t.w);
        }
        m4 = redmax4(m4);
        float4 s4 = make_float4(0.f, 0.f, 0.f, 0.f);
        for (int i = lane; i < deg; i += 64) {
            int s = col[r0 + i];
            float4 a = *(const float4*)(al + (size_t)s * 4);
            float4 t = lrelu4(arv, a);
            s4.x += __expf(t.x - m4.x); s4.y += __expf(t.y - m4.y);
            s4.z += __expf(t.z - m4.z); s4.w += __expf(t.w - m4.w);
        }
        s4 = redsum4(s4);
        inv4 = make_float4(1.f/(s4.x+1e-16f), 1.f/(s4.y+1e-16f),
                           1.f/(s4.z+1e-16f), 1.f/(s4.w+1e-16f));
        for (int c0 = 0; c0 < deg; c0 += 64) {
            int cn = min(64, deg - c0);
            if (lane < cn) {
                int s = col[r0 + c0 + lane];
                float4 a = *(const float4*)(al + (size_t)s * 4);
                float4 t = lrelu4(arv, a);
                float4 p;
                p.x = __expf(t.x - m4.x); p.y = __expf(t.y - m4.y);
                p.z = __expf(t.z - m4.z); p.w = __expf(t.w - m4.w);
                wlds[wid][lane] = p; slds[wid][lane] = s;
            }
            __asm__ volatile("s_waitcnt lgkmcnt(0)" ::: "memory");
            __builtin_amdgcn_sched_barrier(0);
            agg_chunk2(&slds[wid][0], wl, cn, q, xp, A, B, C, D);
            __asm__ volatile("s_waitcnt lgkmcnt(0)" ::: "memory");
            __builtin_amdgcn_sched_barrier(0);
        }
    }
    float invh = (h == 0) ? inv4.x : (h == 1) ? inv4.y : (h == 2) ? inv4.z : inv4.w;
    f32x4 T;
#pragma unroll
    for (int j = 0; j < 4; ++j) {
        T[j] = A[j] + B[j] + C[j] + D[j];
        T[j] += __shfl_xor(T[j], 32);
    }
    if (q == 0) {
        float4 o4 = make_float4(T[0]*invh, T[1]*invh, T[2]*invh, T[3]*invh);
        *(float4*)(out + (size_t)node * DIM + c32 * 4) = o4;
    }
}

// ---------------- graph pooling: segmented (batch is sorted) ----------------
__global__ __launch_bounds__(256) void pool_nodes_seg(
    const float* __restrict__ h, const int* __restrict__ batch,
    float* __restrict__ pooled, int n)
{
    int wid = threadIdx.x >> 6;
    int lane = threadIdx.x & 63;
    int start = blockIdx.x * POOL_CHUNK;
    int end = min(start + POOL_CHUNK, n);
    float a0 = 0.f, a1 = 0.f;
    int curg = -1;
    for (int node = start + wid; node < end; node += 4) {
        int g = batch[node];
        if (g != curg) {
            if (curg >= 0) {
                unsafeAtomicAdd(pooled + (size_t)curg * DIM + lane*2,     a0);
                unsafeAtomicAdd(pooled + (size_t)curg * DIM + lane*2 + 1, a1);
            }
            curg = g; a0 = 0.f; a1 = 0.f;
        }
        float2 v = *(const float2*)(h + (size_t)node * DIM + lane * 2);
        a0 += fmaxf(v.x, 0.f);
        a1 += fmaxf(v.y, 0.f);
    }
    if (curg >= 0) {
        unsafeAtomicAdd(pooled + (size_t)curg * DIM + lane*2,     a0);
        unsafeAtomicAdd(pooled + (size_t)curg * DIM + lane*2 + 1, a1);
    }
}

// ---------------- final projection ----------------
__global__ __launch_bounds__(256) void proj_out(
    const float* __restrict__ pooled, const float* __restrict__ W,
    const float* __restrict__ b, float* __restrict__ out, int G)
{
    int idx = blockIdx.x * blockDim.x + threadIdx.x;
    if (idx >= G * 32) return;
    int g = idx >> 5, j = idx & 31;
    const float* pr = pooled + (size_t)g * DIM;
    const float* wr = W + (size_t)j * DIM;
    float acc = 0.f;
#pragma unroll
    for (int k = 0; k < DIM; ++k) acc = fmaf(pr[k], wr[k], acc);
    out[idx] = acc + b[j];
}

extern "C" void kernel_launch(void* const* d_in, const int* in_sizes, int n_in,
                              void* d_out, int out_size, void* d_ws, size_t ws_size,
                              hipStream_t stream)
{
    const float* x      = (const float*)d_in[0];
    const int*   eidx   = (const int*)d_in[1];
    const int*   batch  = (const int*)d_in[2];
    const float* Ws     = (const float*)d_in[3];
    const float* bs     = (const float*)d_in[4];
    const float* attls  = (const float*)d_in[5];
    const float* attrs  = (const float*)d_in[6];
    const float* projW  = (const float*)d_in[7];
    const float* projb  = (const float*)d_in[8];

    const int N = in_sizes[0] / DIM;
    const int E = in_sizes[1] / 2;
    const int G = out_size / 32;
    const int* src = eidx;
    const int* dst = eidx + E;

    char* ws = (char*)d_ws;
    size_t o = 0;
    auto alloc = [&](size_t bytes) { char* p = ws + o; o += (bytes + 255) & ~255ull; return p; };
    float*  hA     = (float*)alloc((size_t)N * DIM * 4);
    float*  hB     = (float*)alloc((size_t)N * DIM * 4);
    __bf16* xlb    = (__bf16*)alloc((size_t)N * DIM * 2);
    float*  al     = (float*)alloc((size_t)N * 4 * 4);
    float*  ar     = (float*)alloc((size_t)N * 4 * 4);
    int*    rowptr = (int*)alloc((size_t)(N + 1) * 4);
    int*    wpos   = (int*)alloc((size_t)N * 4);
    int*    deg    = (int*)alloc((size_t)N * 4);
    int*    colv   = (int*)alloc((size_t)E * 4);
    int*    parts  = (int*)alloc(256 * 4);
    float*  pooled = (float*)alloc((size_t)G * DIM * 4);
    __bf16* Wb     = (__bf16*)alloc((size_t)3 * 16384 * 2);

    // ---- one-time prep: W fragment pack + CSR build ----
    const int wtot = 3 * 16384;
    pack_w<<<(wtot + 255) / 256, 256, 0, stream>>>(Ws, Wb, wtot);

    const int nb = (N + 1023) / 1024;
    hipMemsetAsync(deg, 0, (size_t)N * 4, stream);
    deg_count<<<(E + 255) / 256, 256, 0, stream>>>(dst, deg, E);
    scan_blocks<<<nb, 256, 0, stream>>>(deg, rowptr, parts, N);
    scan_partials<<<1, 256, 0, stream>>>(parts, nb, rowptr, N);
    add_offsets<<<nb, 256, 0, stream>>>(rowptr, wpos, parts, N);
    scatter_edges<<<(E + 255) / 256, 256, 0, stream>>>(src, dst, wpos, colv, E);

    // ---- 3 GAT layers ----
    const float* hin = x;
    float* houts[3] = {hA, hB, hA};
    for (int l = 0; l < 3; ++l) {
        float* hout = houts[l];
        dim3 gb((N + 63) / 64);
        const uint4* Wb4 = (const uint4*)(Wb + (size_t)l * 16384);
        if (l == 0)
            gemm_mfma<false><<<gb, 256, 0, stream>>>(hin, Wb4, bs + l*DIM,
                attls + l*DIM, attrs + l*DIM, xlb, al, ar, N);
        else
            gemm_mfma<true ><<<gb, 256, 0, stream>>>(hin, Wb4, bs + l*DIM,
                attls + l*DIM, attrs + l*DIM, xlb, al, ar, N);
        gat_aggregate<<<(N + 3) / 4, 256, 0, stream>>>(rowptr, colv, al, ar,
            (const unsigned short*)xlb, hout, N);
        hin = hout;
    }

    // ---- pool + projection ----
    hipMemsetAsync(pooled, 0, (size_t)G * DIM * 4, stream);
    pool_nodes_seg<<<(N + POOL_CHUNK - 1) / POOL_CHUNK, 256, 0, stream>>>(hA, batch, pooled, N);
    proj_out<<<(G * 32 + 255) / 256, 256, 0, stream>>>(pooled, projW, projb, (float*)d_out, G);
}